// Round 9
// baseline (973.361 us; speedup 1.0000x reference)
//
#include <hip/hip_runtime.h>
#include <math.h>

#define HW 65536
#define NAG 5
#define EPSF 1e-8f

typedef __attribute__((ext_vector_type(8))) short short8;
typedef __attribute__((ext_vector_type(4))) float f32x4;

__device__ __forceinline__ unsigned short f2bf(float f) {
    union { float f; unsigned int u; } v; v.f = f;
    unsigned int r = v.u + 0x7FFF + ((v.u >> 16) & 1);
    return (unsigned short)(r >> 16);
}

__device__ __forceinline__ void gload_lds16(const unsigned short* g, unsigned short* l) {
    __builtin_amdgcn_global_load_lds(
        (__attribute__((address_space(1))) void*)(g),
        (__attribute__((address_space(3))) void*)(l),
        16, 0, 0);
}

// XCD-chunked bijective swizzle for nwg=1280 (1280 % 8 == 0, chunk=160)
__device__ __forceinline__ int swz1280(int orig) {
    return (orig & 7) * 160 + (orig >> 3);
}

__device__ __forceinline__ f32x4 MF(short8 a, short8 b, f32x4 c) {
    return __builtin_amdgcn_mfma_f32_16x16x32_bf16(a, b, c, 0, 0, 0);
}

// ---------------------------------------------------------------------------
// ws layout (float offsets):
//   pool [0,464)  qwT [464,1488)  kw1T [1488,1616)  kw2T [1616,2640)
//   kw3T [2640,2768)
//   wbf  [122576,159440) : se_w1 bf16 [tap][mid=128][c=64]
//   w2bf [159440,161488) : se_w2 bf16 [j=32][mid=128]
//   wspf [161488,179920) : sp_w1 feat bf16 [tap][mid=64][c=64]
//   wspv [179920,189136) : sp_w1 vox/det bf16 [tap][mid=64][c=32]
//   featNHWC [189136, 10674896)  : [5][256][256][64] bf16, pos p holds ch p^((x&7)<<3)
//   vdNHWC   [10674896, 15917776): [5][256][256][32] bf16, pos p holds ch p^((x&3)<<3)
//   partials [15917776, 16036560): [464][256] per-(channel,y) row sums
// ---------------------------------------------------------------------------

__global__ __launch_bounds__(256) void k_transpose(
    const float* __restrict__ q_w, const float* __restrict__ k_w1,
    const float* __restrict__ k_w2, const float* __restrict__ k_w3,
    float* __restrict__ qwT, float* __restrict__ kw1T,
    float* __restrict__ kw2T, float* __restrict__ kw3T)
{
    int i = blockIdx.x * 256 + threadIdx.x;
    if (i < 1024)  { int o = i / 64,  c = i % 64;  qwT[c * 16 + o] = q_w[i];
                                                   kw2T[c * 16 + o] = k_w2[i]; }
    if (i < 128)   { int o = i / 8,   c = i % 8;   kw1T[c * 16 + o] = k_w1[i];
                                                   kw3T[c * 16 + o] = k_w3[i]; }
}

__global__ __launch_bounds__(256) void k_prep(
    const float* __restrict__ se_w1, const float* __restrict__ se_w2,
    const float* __restrict__ sp_w1,
    unsigned short* __restrict__ wbf, unsigned short* __restrict__ w2bf,
    unsigned short* __restrict__ wspf, unsigned short* __restrict__ wspv)
{
    int i = blockIdx.x * 256 + threadIdx.x;
    if (i < 73728) {
        int c = i & 63, mid = (i >> 6) & 127, tap = i >> 13;
        wbf[i] = f2bf(se_w1[(mid * 64 + c) * 9 + tap]);
    }
    if (i < 4096) w2bf[i] = f2bf(se_w2[i]);
    if (i < 36864) {
        int c = i & 63, mid = (i >> 6) & 63, tap = i >> 12;
        wspf[i] = f2bf(sp_w1[(mid * 80 + 8 + c) * 9 + tap]);
    }
    if (i < 18432) {
        int c = i & 31, mid = (i >> 5) & 63, tap = i >> 11;
        float v = 0.f;
        if (c < 8)       v = sp_w1[(mid * 80 + c) * 9 + tap];
        else if (c < 16) v = sp_w1[(mid * 80 + 64 + c) * 9 + tap];
        wspv[i] = f2bf(v);
    }
}

// ---------------------------------------------------------------------------
// NHWC prep: fp32 planes -> bf16 NHWC (pre-swizzled) + per-(channel,y) sums.
// ---------------------------------------------------------------------------
__global__ __launch_bounds__(256) void k_prep_nhwc(
    const float* __restrict__ ego_feat,
    const float* __restrict__ collab_vox, const float* __restrict__ collab_feat,
    const float* __restrict__ collab_det,
    unsigned short* __restrict__ featNHWC, unsigned short* __restrict__ vdNHWC,
    float* __restrict__ partials)
{
    __shared__ float lds_f[64 * 65];
    const int y = blockIdx.x, n = blockIdx.y;
    const int t = threadIdx.x;
    const bool ego = (n == 5);
    const float* featsrc = ego ? ego_feat : collab_feat + (size_t)n * 64 * HW;

    float psum = 0.f;
    const int c_ld = t >> 2, q0 = t & 3;
    for (int chunk = 0; chunk < 4; ++chunk) {
        const int x0c = chunk * 64;
        __syncthreads();
#pragma unroll
        for (int q = q0; q < 16; q += 4) {
            float4 v = *(const float4*)&featsrc[(size_t)c_ld * HW + y * 256 + x0c + q * 4];
            lds_f[c_ld * 65 + q * 4 + 0] = v.x;
            lds_f[c_ld * 65 + q * 4 + 1] = v.y;
            lds_f[c_ld * 65 + q * 4 + 2] = v.z;
            lds_f[c_ld * 65 + q * 4 + 3] = v.w;
            psum += (v.x + v.y) + (v.z + v.w);
        }
        __syncthreads();
        if (!ego) {
#pragma unroll
            for (int half = 0; half < 2; ++half) {
                int g = t & 7, xl = (t >> 3) + half * 32;
                int x = x0c + xl;
                int cg = g ^ (x & 7);
                unsigned short pk[8];
#pragma unroll
                for (int i = 0; i < 8; ++i)
                    pk[i] = f2bf(lds_f[(cg * 8 + i) * 65 + xl]);
                *(short8*)&featNHWC[(((size_t)n * 256 + y) * 256 + x) * 64 + g * 8] =
                    *(const short8*)pk;
            }
        }
    }
    psum += __shfl_xor(psum, 1, 64);
    psum += __shfl_xor(psum, 2, 64);
    if (q0 == 0) {
        int row = ego ? c_ld : 64 + n * 80 + 8 + c_ld;
        partials[row * 256 + y] = psum;
    }
    if (ego) return;

    float psv = 0.f;
    const int c2 = t >> 4, q2 = t & 15;
    const float* vdsrc = (c2 < 8) ? collab_vox + ((size_t)n * 8 + c2) * HW
                                  : collab_det + ((size_t)n * 8 + (c2 - 8)) * HW;
    for (int chunk = 0; chunk < 4; ++chunk) {
        const int x0c = chunk * 64;
        __syncthreads();
        {
            float4 v = *(const float4*)&vdsrc[y * 256 + x0c + q2 * 4];
            lds_f[c2 * 65 + q2 * 4 + 0] = v.x;
            lds_f[c2 * 65 + q2 * 4 + 1] = v.y;
            lds_f[c2 * 65 + q2 * 4 + 2] = v.z;
            lds_f[c2 * 65 + q2 * 4 + 3] = v.w;
            psv += (v.x + v.y) + (v.z + v.w);
        }
        __syncthreads();
        {
            int g = t & 3, xl = t >> 2;
            int x = x0c + xl;
            int cg = g ^ (x & 3);
            unsigned short pk[8];
#pragma unroll
            for (int i = 0; i < 8; ++i) {
                int cc = cg * 8 + i;
                pk[i] = (cc < 16) ? f2bf(lds_f[cc * 65 + xl]) : (unsigned short)0;
            }
            *(short8*)&vdNHWC[(((size_t)n * 256 + y) * 256 + x) * 32 + g * 8] =
                *(const short8*)pk;
        }
    }
    psv += __shfl_xor(psv, 1, 64);
    psv += __shfl_xor(psv, 2, 64);
    psv += __shfl_xor(psv, 4, 64);
    psv += __shfl_xor(psv, 8, 64);
    if (q2 == 0) {
        int row = 64 + n * 80 + (c2 < 8 ? c2 : c2 + 64);
        partials[row * 256 + y] = psv;
    }
}

__global__ __launch_bounds__(256) void k_pool2(
    const float* __restrict__ partials, float* __restrict__ pool)
{
    __shared__ float red[256];
    int r = blockIdx.x, t = threadIdx.x;
    red[t] = partials[r * 256 + t];
    __syncthreads();
    for (int s = 128; s > 0; s >>= 1) {
        if (t < s) red[t] += red[t + s];
        __syncthreads();
    }
    if (t == 0) pool[r] = red[0] * (1.f / HW);
}

// ---------------------------------------------------------------------------
// contribution + qk_attn : one thread per (agent, pixel)
// ---------------------------------------------------------------------------
__global__ __launch_bounds__(256) void k_contrib_qk(
    const float* __restrict__ ego_vox, const float* __restrict__ ego_feat,
    const float* __restrict__ ego_det,
    const float* __restrict__ collab_vox, const float* __restrict__ collab_feat,
    const float* __restrict__ collab_det,
    const float* __restrict__ qw, const float* __restrict__ kw1,
    const float* __restrict__ kw2, const float* __restrict__ kw3,
    float* __restrict__ out_contrib, float* __restrict__ out_qk)
{
    const int n = blockIdx.x >> 8;
    const int p = ((blockIdx.x & 255) << 8) | threadIdx.x;

    float q[16], k2[16];
#pragma unroll
    for (int o = 0; o < 16; o++) { q[o] = 0.f; k2[o] = 0.f; }
    float sq_ref = 0.f, dot_f = 0.f, sq_cf = 0.f;
#pragma unroll 4
    for (int c = 0; c < 64; c++) {
        float e = ego_feat[c * HW + p];
        float x = collab_feat[(n * 64 + c) * HW + p];
        sq_ref = fmaf(e, e, sq_ref);
        dot_f  = fmaf(x, e, dot_f);
        sq_cf  = fmaf(x, x, sq_cf);
#pragma unroll
        for (int o = 0; o < 16; o++) {
            q[o]  = fmaf(qw[c * 16 + o], e, q[o]);
            k2[o] = fmaf(kw2[c * 16 + o], x, k2[o]);
        }
    }
    float kx[16];
#pragma unroll
    for (int o = 0; o < 16; o++) kx[o] = 0.f;
    float dot_v = 0.f, sq_cv = 0.f;
#pragma unroll
    for (int c = 0; c < 8; c++) {
        float e = ego_vox[c * HW + p];
        float x = collab_vox[(n * 8 + c) * HW + p];
        sq_ref = fmaf(e, e, sq_ref);
        dot_v  = fmaf(x, e, dot_v);
        sq_cv  = fmaf(x, x, sq_cv);
#pragma unroll
        for (int o = 0; o < 16; o++)
            kx[o] = fmaf(kw1[c * 16 + o], x, kx[o]);
    }
    float s1 = 0.f;
#pragma unroll
    for (int o = 0; o < 16; o++) s1 = fmaf(q[o], kx[o], s1);
#pragma unroll
    for (int o = 0; o < 16; o++) kx[o] = 0.f;
    float dot_d = 0.f, sq_cd = 0.f;
#pragma unroll
    for (int c = 0; c < 8; c++) {
        float e = ego_det[c * HW + p];
        float x = collab_det[(n * 8 + c) * HW + p];
        sq_ref = fmaf(e, e, sq_ref);
        dot_d  = fmaf(x, e, dot_d);
        sq_cd  = fmaf(x, x, sq_cd);
#pragma unroll
        for (int o = 0; o < 16; o++)
            kx[o] = fmaf(kw3[c * 16 + o], x, kx[o]);
    }
    float s3 = 0.f, s2 = 0.f;
#pragma unroll
    for (int o = 0; o < 16; o++) { s3 = fmaf(q[o], kx[o], s3); s2 = fmaf(q[o], k2[o], s2); }

    float inv_ref = 1.f / fmaxf(sqrtf(sq_ref), EPSF);
    float simv = dot_v / fmaxf(sqrtf(sq_cv), EPSF) * inv_ref;
    float simf = dot_f / fmaxf(sqrtf(sq_cf), EPSF) * inv_ref;
    float simd_ = dot_d / fmaxf(sqrtf(sq_cd), EPSF) * inv_ref;
    out_contrib[(n * 3 + 0) * HW + p] = (simv + 1.f) * 0.5f;
    out_contrib[(n * 3 + 1) * HW + p] = (simf + 1.f) * 0.5f;
    out_contrib[(n * 3 + 2) * HW + p] = (simd_ + 1.f) * 0.5f;

    s1 *= 0.25f; s2 *= 0.25f; s3 *= 0.25f;
    float m = fmaxf(s1, fmaxf(s2, s3));
    float e1 = __expf(s1 - m), e2 = __expf(s2 - m), e3 = __expf(s3 - m);
    float inv = 1.f / (e1 + e2 + e3);
    out_qk[(n * 3 + 0) * HW + p] = e1 * inv;
    out_qk[(n * 3 + 1) * HW + p] = e2 * inv;
    out_qk[(n * 3 + 2) * HW + p] = e3 * inv;
}

// ---------------------------------------------------------------------------
__global__ __launch_bounds__(192) void k_mlps(
    const float* __restrict__ pool,
    const float* __restrict__ ch_w1, const float* __restrict__ ch_w2,
    const float* __restrict__ gr_w1, const float* __restrict__ gr_b1,
    const float* __restrict__ gr_w2, const float* __restrict__ gr_b2,
    float* __restrict__ out_gran, float* __restrict__ out_chan)
{
    __shared__ float h4[4], h32[5][32], logit[5][3];
    int t = threadIdx.x;
    if (t < 4) {
        float a = 0.f;
        for (int c = 0; c < 64; c++) a = fmaf(ch_w1[t * 64 + c], pool[c], a);
        h4[t] = fmaxf(a, 0.f);
    }
    if (t < 160) {
        int n = t >> 5, i = t & 31;
        float a = gr_b1[i];
        for (int c = 0; c < 80; c++) a = fmaf(gr_w1[i * 80 + c], pool[64 + n * 80 + c], a);
        h32[n][i] = fmaxf(a, 0.f);
    }
    __syncthreads();
    if (t < 64) {
        float m = 0.f;
#pragma unroll
        for (int j = 0; j < 4; j++) m = fmaf(ch_w2[t * 4 + j], h4[j], m);
        out_chan[t] = 1.f / (1.f + __expf(-2.f * m));
    }
    if (t < 15) {
        int n = t / 3, j = t % 3;
        float a = gr_b2[j];
#pragma unroll
        for (int i = 0; i < 32; i++) a = fmaf(gr_w2[j * 32 + i], h32[n][i], a);
        logit[n][j] = a;
    }
    __syncthreads();
    if (t < 5) {
        float a = logit[t][0], b = logit[t][1], c = logit[t][2];
        float m = fmaxf(a, fmaxf(b, c));
        float ea = __expf(a - m), eb = __expf(b - m), ec = __expf(c - m);
        float inv = 1.f / (ea + eb + ec);
        out_gran[t * 3 + 0] = ea * inv;
        out_gran[t * 3 + 1] = eb * inv;
        out_gran[t * 3 + 2] = ec * inv;
    }
}

// ---------------------------------------------------------------------------
// semantic attention v6: LDS = stage buffer ONLY (50688 B -> 3 blocks/CU).
// GEMM1 unchanged; GEMM2 runs in two 128-px halves overlaying the dead
// stage buffer (P-half = 32 KB < 49.5 KB).
// ---------------------------------------------------------------------------
__global__ __launch_bounds__(512, 6) void k_sem_nhwc(
    const unsigned short* __restrict__ featNHWC,
    const unsigned short* __restrict__ wbf,   // [9][128][64]
    const unsigned short* __restrict__ w2bf,  // [32][128]
    const float* __restrict__ se_b1, const float* __restrict__ se_b2,
    float* __restrict__ out_sem)
{
    __shared__ __align__(16) unsigned short smem[6 * 66 * 64];  // 50688 B
    const int bid = swz1280((int)blockIdx.x);
    const int n = bid >> 8, rem = bid & 255;
    const int x0 = (rem & 3) << 6, y0 = (rem >> 2) << 2;
    const int tid = threadIdx.x, lane = tid & 63, w = tid >> 6;
    const int wr = w >> 1, wc = w & 1;
    const int l15 = lane & 15, lg = lane >> 4;
    const short8 z8 = {0, 0, 0, 0, 0, 0, 0, 0};

    if (y0 == 0)
        for (int i = tid; i < 528; i += 512) *(short8*)&smem[i * 8] = z8;
    if (y0 == 252)
        for (int i = tid; i < 528; i += 512) *(short8*)&smem[5 * 66 * 64 + i * 8] = z8;

    for (int idx = w; idx < 48; idx += 8) {
        int dy = idx >> 3, k = idx & 7, gy = y0 - 1 + dy;
        if ((unsigned)gy < 256u)
            gload_lds16(
                &featNHWC[(((size_t)n * 256 + gy) * 256 + x0 + k * 8 + (lane >> 3)) * 64 + (lane & 7) * 8],
                &smem[(dy * 66 + 1 + k * 8) * 64]);
    }
    if (tid < 96) {
        int dy = tid >> 4, rem2 = tid & 15, side = rem2 >> 3, c8 = rem2 & 7;
        int gy = y0 - 1 + dy, gx = side ? x0 + 64 : x0 - 1, col = side ? 65 : 0;
        short8 v = z8;
        if ((unsigned)gy < 256u && (unsigned)gx < 256u)
            v = *(const short8*)&featNHWC[(((size_t)n * 256 + gy) * 256 + gx) * 64 + c8 * 8];
        *(short8*)&smem[(dy * 66 + col) * 64 + c8 * 8] = v;
    }
    __syncthreads();

    // ---- GEMM1 (unchanged): acc[mf][nf] at pixel = mf*16+lg*4+rr (in wave's
    //      row wr), mid = wc*64 + nf*16 + l15 ----
    const int midb = wc * 64 + l15;
    f32x4 acc[4][4] = {};
    short8 bc[4], bn[4];
#pragma unroll
    for (int nf = 0; nf < 4; ++nf)
        bc[nf] = *(const short8*)&wbf[(0 * 128 + midb + nf * 16) * 64 + lg * 8];

#pragma unroll 1
    for (int p = 0; p < 18; ++p) {
        const int tap = p >> 1, kc = p & 1;
        const int dyrow = tap / 3, dx = tap % 3;
        const int pn = (p < 17) ? p + 1 : 17;
        const int tapn = pn >> 1, kcn = pn & 1;
#pragma unroll
        for (int nf = 0; nf < 4; ++nf)
            bn[nf] = *(const short8*)&wbf[(tapn * 128 + midb + nf * 16) * 64 + kcn * 32 + lg * 8];
        const int c0 = kc * 32 + lg * 8;
        const int dyb = (wr + dyrow) * 66;
        short8 a[4];
#pragma unroll
        for (int mf = 0; mf < 4; ++mf) {
            int col = mf * 16 + l15 + dx;
            a[mf] = *(const short8*)&smem[(dyb + col) * 64 + (c0 ^ (((col + 7) & 7) << 3))];
        }
        __builtin_amdgcn_s_setprio(1);
#pragma unroll
        for (int mf = 0; mf < 4; ++mf)
#pragma unroll
            for (int nf = 0; nf < 4; ++nf)
                acc[mf][nf] = MF(a[mf], bc[nf], acc[mf][nf]);
        __builtin_amdgcn_s_setprio(0);
#pragma unroll
        for (int nf = 0; nf < 4; ++nf) bc[nf] = bn[nf];
    }
    __syncthreads();  // all waves done reading stage -> buffer reusable as P

    // ---- GEMM2 in two 128-px halves (rows {0,1} then {2,3}) ----
#pragma unroll 1
    for (int h = 0; h < 2; ++h) {
        // waves owning rows 2h, 2h+1 write their relu(mid+b1) into P[128][128]
        if ((wr >> 1) == h) {
            const int rbase = (wr & 1) * 64;
#pragma unroll
            for (int nf = 0; nf < 4; ++nf) {
                int mid = wc * 64 + nf * 16 + l15;
                float b1 = se_b1[mid];
#pragma unroll
                for (int mf = 0; mf < 4; ++mf) {
                    int mrow = rbase + mf * 16 + lg * 4;
#pragma unroll
                    for (int rr = 0; rr < 4; ++rr) {
                        int m = mrow + rr;
                        float v = fmaxf(acc[mf][nf][rr] + b1, 0.f);
                        smem[m * 128 + (mid ^ ((m & 7) << 3))] = f2bf(v);
                    }
                }
            }
        }
        __syncthreads();

        // all 8 waves: GEMM2 on P[128][128]; wave's m-chunk = w*16
        f32x4 acc2[2] = {};
        const int pxb = w * 16;
#pragma unroll
        for (int kc = 0; kc < 4; ++kc) {
            const int k0 = kc * 32 + lg * 8;
            int m = pxb + l15;
            short8 a2 = *(const short8*)&smem[m * 128 + (k0 ^ ((m & 7) << 3))];
            short8 b2[2];
#pragma unroll
            for (int nf = 0; nf < 2; ++nf) {
                int j = nf * 16 + l15;
                b2[nf] = *(const short8*)&w2bf[j * 128 + k0];
            }
#pragma unroll
            for (int nf = 0; nf < 2; ++nf)
                acc2[nf] = MF(a2, b2[nf], acc2[nf]);
        }
#pragma unroll
        for (int nf = 0; nf < 2; ++nf) {
            int j = nf * 16 + l15;
            float bj = se_b2[j];
            int m = pxb + lg * 4;           // D row (within half)
            int oy = h * 2 + (m >> 6), x = m & 63;
            float4 v;
            v.x = acc2[nf][0] + bj; v.y = acc2[nf][1] + bj;
            v.z = acc2[nf][2] + bj; v.w = acc2[nf][3] + bj;
            *(float4*)&out_sem[(size_t)(n * 32 + j) * HW + (y0 + oy) * 256 + x0 + x] = v;
        }
        if (h == 0) __syncthreads();  // before overwriting P with half 1
    }
}

// ---------------------------------------------------------------------------
// spatial attention v5 (unchanged from R7 — proven)
// ---------------------------------------------------------------------------
__global__ __launch_bounds__(512, 4) void k_spatial_nhwc(
    const unsigned short* __restrict__ featNHWC,
    const unsigned short* __restrict__ vdNHWC,
    const unsigned short* __restrict__ wspf,  // [9][64][64]
    const unsigned short* __restrict__ wspv,  // [9][64][32]
    const float* __restrict__ sp_b1, const float* __restrict__ sp_w2,
    const float* __restrict__ sp_b2,
    float* __restrict__ out_sp)
{
    __shared__ __align__(16) unsigned short sF[6 * 66 * 64];  // 50688 B
    __shared__ __align__(16) unsigned short sV[6 * 66 * 32];  // 25344 B
    const int bid = swz1280((int)blockIdx.x);
    const int n = bid >> 8, rem = bid & 255;
    const int x0 = (rem & 3) << 6, y0 = (rem >> 2) << 2;
    const int tid = threadIdx.x, lane = tid & 63, w = tid >> 6;
    const int l15 = lane & 15, lg = lane >> 4;
    const int wr = w >> 1, wc = w & 1;
    const short8 z8 = {0, 0, 0, 0, 0, 0, 0, 0};

    if (y0 == 0) {
        for (int i = tid; i < 528; i += 512) *(short8*)&sF[i * 8] = z8;
        for (int i = tid; i < 264; i += 512) *(short8*)&sV[i * 8] = z8;
    }
    if (y0 == 252) {
        for (int i = tid; i < 528; i += 512) *(short8*)&sF[5 * 66 * 64 + i * 8] = z8;
        for (int i = tid; i < 264; i += 512) *(short8*)&sV[5 * 66 * 32 + i * 8] = z8;
    }
    for (int idx = w; idx < 48; idx += 8) {
        int dy = idx >> 3, k = idx & 7, gy = y0 - 1 + dy;
        if ((unsigned)gy < 256u)
            gload_lds16(
                &featNHWC[(((size_t)n * 256 + gy) * 256 + x0 + k * 8 + (lane >> 3)) * 64 + (lane & 7) * 8],
                &sF[(dy * 66 + 1 + k * 8) * 64]);
    }
    for (int idx = w; idx < 24; idx += 8) {
        int dy = idx >> 2, k = idx & 3, gy = y0 - 1 + dy;
        if ((unsigned)gy < 256u)
            gload_lds16(
                &vdNHWC[(((size_t)n * 256 + gy) * 256 + x0 + k * 16 + (lane >> 2)) * 32 + (lane & 3) * 8],
                &sV[(dy * 66 + 1 + k * 16) * 32]);
    }
    if (tid < 96) {
        int dy = tid >> 4, rem2 = tid & 15, side = rem2 >> 3, c8 = rem2 & 7;
        int gy = y0 - 1 + dy, gx = side ? x0 + 64 : x0 - 1, col = side ? 65 : 0;
        short8 v = z8;
        if ((unsigned)gy < 256u && (unsigned)gx < 256u)
            v = *(const short8*)&featNHWC[(((size_t)n * 256 + gy) * 256 + gx) * 64 + c8 * 8];
        *(short8*)&sF[(dy * 66 + col) * 64 + c8 * 8] = v;
    } else if (tid < 144) {
        int t2 = tid - 96;
        int dy = t2 >> 3, rem2 = t2 & 7, side = rem2 >> 2, g4 = rem2 & 3;
        int gy = y0 - 1 + dy, gx = side ? x0 + 64 : x0 - 1, col = side ? 65 : 0;
        short8 v = z8;
        if ((unsigned)gy < 256u && (unsigned)gx < 256u)
            v = *(const short8*)&vdNHWC[(((size_t)n * 256 + gy) * 256 + gx) * 32 + g4 * 8];
        *(short8*)&sV[(dy * 66 + col) * 32 + g4 * 8] = v;
    }
    __syncthreads();

    f32x4 acc[4][2] = {};
    const int mid0 = wc * 32 + l15, mid1 = wc * 32 + 16 + l15;

    short8 bc0 = *(const short8*)&wspf[(0 * 64 + mid0) * 64 + lg * 8];
    short8 bc1 = *(const short8*)&wspf[(0 * 64 + mid1) * 64 + lg * 8];
#pragma unroll 1
    for (int p = 0; p < 18; ++p) {
        const int tap = p >> 1, kc = p & 1;
        const int dyrow = tap / 3, dx = tap % 3;
        const int pn = (p < 17) ? p + 1 : 17;
        const int tapn = pn >> 1, kcn = pn & 1;
        short8 bn0 = *(const short8*)&wspf[(tapn * 64 + mid0) * 64 + kcn * 32 + lg * 8];
        short8 bn1 = *(const short8*)&wspf[(tapn * 64 + mid1) * 64 + kcn * 32 + lg * 8];
        const int c0 = kc * 32 + lg * 8;
        const int dyb = (wr + dyrow) * 66;
        short8 a[4];
#pragma unroll
        for (int mf = 0; mf < 4; ++mf) {
            int col = mf * 16 + l15 + dx;
            a[mf] = *(const short8*)&sF[(dyb + col) * 64 + (c0 ^ (((col + 7) & 7) << 3))];
        }
        __builtin_amdgcn_s_setprio(1);
#pragma unroll
        for (int mf = 0; mf < 4; ++mf) {
            acc[mf][0] = MF(a[mf], bc0, acc[mf][0]);
            acc[mf][1] = MF(a[mf], bc1, acc[mf][1]);
        }
        __builtin_amdgcn_s_setprio(0);
        bc0 = bn0; bc1 = bn1;
    }

    const int c0v = lg * 8;
    short8 vc0 = *(const short8*)&wspv[(0 * 64 + mid0) * 32 + c0v];
    short8 vc1 = *(const short8*)&wspv[(0 * 64 + mid1) * 32 + c0v];
#pragma unroll 1
    for (int tap = 0; tap < 9; ++tap) {
        const int dyrow = tap / 3, dx = tap % 3;
        const int tapn = (tap < 8) ? tap + 1 : 8;
        short8 vn0 = *(const short8*)&wspv[(tapn * 64 + mid0) * 32 + c0v];
        short8 vn1 = *(const short8*)&wspv[(tapn * 64 + mid1) * 32 + c0v];
        const int dyb = (wr + dyrow) * 66;
        short8 a[4];
#pragma unroll
        for (int mf = 0; mf < 4; ++mf) {
            int col = mf * 16 + l15 + dx;
            a[mf] = *(const short8*)&sV[(dyb + col) * 32 + (c0v ^ (((col + 3) & 3) << 3))];
        }
        __builtin_amdgcn_s_setprio(1);
#pragma unroll
        for (int mf = 0; mf < 4; ++mf) {
            acc[mf][0] = MF(a[mf], vc0, acc[mf][0]);
            acc[mf][1] = MF(a[mf], vc1, acc[mf][1]);
        }
        __builtin_amdgcn_s_setprio(0);
        vc0 = vn0; vc1 = vn1;
    }

    const float w2v0 = sp_w2[mid0], w2v1 = sp_w2[mid1];
    const float b1v0 = sp_b1[mid0], b1v1 = sp_b1[mid1];
    float4 part[4];
#pragma unroll
    for (int mf = 0; mf < 4; ++mf) {
#pragma unroll
        for (int rr = 0; rr < 4; ++rr) {
            float s = fmaf(w2v0, fmaxf(acc[mf][0][rr] + b1v0, 0.f),
                           w2v1 * fmaxf(acc[mf][1][rr] + b1v1, 0.f));
            s += __shfl_xor(s, 1, 64);
            s += __shfl_xor(s, 2, 64);
            s += __shfl_xor(s, 4, 64);
            s += __shfl_xor(s, 8, 64);
            ((float*)&part[mf])[rr] = s;
        }
    }
    __syncthreads();
    float4* sP = (float4*)sV;
    if (wc == 1 && l15 == 0) {
#pragma unroll
        for (int mf = 0; mf < 4; ++mf) sP[(wr * 4 + mf) * 4 + lg] = part[mf];
    }
    __syncthreads();
    if (wc == 0 && l15 == 0) {
        const float b2 = sp_b2[0];
#pragma unroll
        for (int mf = 0; mf < 4; ++mf) {
            float4 o = sP[(wr * 4 + mf) * 4 + lg];
            float4 vout;
            vout.x = 1.f / (1.f + __expf(-(part[mf].x + o.x + b2)));
            vout.y = 1.f / (1.f + __expf(-(part[mf].y + o.y + b2)));
            vout.z = 1.f / (1.f + __expf(-(part[mf].z + o.z + b2)));
            vout.w = 1.f / (1.f + __expf(-(part[mf].w + o.w + b2)));
            *(float4*)&out_sp[(size_t)n * HW + (y0 + wr) * 256 + x0 + mf * 16 + lg * 4] = vout;
        }
    }
}

// ---------------------------------------------------------------------------
extern "C" void kernel_launch(void* const* d_in, const int* in_sizes, int n_in,
                              void* d_out, int out_size, void* d_ws, size_t ws_size,
                              hipStream_t stream)
{
    (void)in_sizes; (void)n_in; (void)out_size; (void)ws_size;
    const float* ego_vox     = (const float*)d_in[0];
    const float* ego_feat    = (const float*)d_in[1];
    const float* ego_det     = (const float*)d_in[2];
    const float* collab_vox  = (const float*)d_in[3];
    const float* collab_feat = (const float*)d_in[4];
    const float* collab_det  = (const float*)d_in[5];
    const float* q_w   = (const float*)d_in[6];
    const float* ch_w1 = (const float*)d_in[7];
    const float* ch_w2 = (const float*)d_in[8];
    const float* k_w1  = (const float*)d_in[9];
    const float* k_w2  = (const float*)d_in[10];
    const float* k_w3  = (const float*)d_in[11];
    const float* sp_w1 = (const float*)d_in[12];
    const float* sp_b1 = (const float*)d_in[13];
    const float* sp_w2 = (const float*)d_in[14];
    const float* sp_b2 = (const float*)d_in[15];
    const float* gr_w1 = (const float*)d_in[16];
    const float* gr_b1 = (const float*)d_in[17];
    const float* gr_w2 = (const float*)d_in[18];
    const float* gr_b2 = (const float*)d_in[19];
    const float* se_w1 = (const float*)d_in[20];
    const float* se_b1 = (const float*)d_in[21];
    const float* se_w2 = (const float*)d_in[22];
    const float* se_b2 = (const float*)d_in[23];

    float* out = (float*)d_out;
    float* o_contrib = out;                 // [5,3,256,256]
    float* o_qk      = out + 983040;        // [5,3,256,256]
    float* o_sp      = out + 1966080;       // [5,1,256,256]
    float* o_gran    = out + 2293760;       // [5,3]
    float* o_sem     = out + 2293775;       // [5,32,256,256]
    float* o_chan    = out + 12779535;      // [64]

    float* wsf  = (float*)d_ws;
    float* pool = wsf;
    float* qwT  = wsf + 464;
    float* kw1T = wsf + 1488;
    float* kw2T = wsf + 1616;
    float* kw3T = wsf + 2640;
    unsigned short* wbf  = (unsigned short*)(wsf + 122576);
    unsigned short* w2bf = (unsigned short*)(wsf + 159440);
    unsigned short* wspf = (unsigned short*)(wsf + 161488);
    unsigned short* wspv = (unsigned short*)(wsf + 179920);
    unsigned short* featNHWC = (unsigned short*)(wsf + 189136);
    unsigned short* vdNHWC   = (unsigned short*)(wsf + 10674896);
    float* partials          = wsf + 15917776;

    k_prep<<<288, 256, 0, stream>>>(se_w1, se_w2, sp_w1, wbf, w2bf, wspf, wspv);
    k_transpose<<<4, 256, 0, stream>>>(q_w, k_w1, k_w2, k_w3, qwT, kw1T, kw2T, kw3T);

    k_contrib_qk<<<1280, 256, 0, stream>>>(
        ego_vox, ego_feat, ego_det, collab_vox, collab_feat, collab_det,
        qwT, kw1T, kw2T, kw3T, o_contrib, o_qk);

    k_prep_nhwc<<<dim3(256, 6), 256, 0, stream>>>(
        ego_feat, collab_vox, collab_feat, collab_det,
        featNHWC, vdNHWC, partials);
    k_pool2<<<464, 256, 0, stream>>>(partials, pool);
    k_mlps<<<1, 192, 0, stream>>>(pool, ch_w1, ch_w2, gr_w1, gr_b1, gr_w2, gr_b2,
                                  o_gran, o_chan);

    k_spatial_nhwc<<<1280, 512, 0, stream>>>(
        featNHWC, vdNHWC, wspf, wspv, sp_b1, sp_w2, sp_b2, o_sp);
    k_sem_nhwc<<<1280, 512, 0, stream>>>(
        featNHWC, wbf, w2bf, se_b1, se_b2, o_sem);
}

// Round 10
// 349.011 us; speedup vs baseline: 2.7889x; 2.7889x over previous
//
#include <hip/hip_runtime.h>
#include <math.h>

#define HW 65536
#define NAG 5
#define EPSF 1e-8f

typedef __attribute__((ext_vector_type(8))) short short8;
typedef __attribute__((ext_vector_type(4))) float f32x4;

__device__ __forceinline__ unsigned short f2bf(float f) {
    union { float f; unsigned int u; } v; v.f = f;
    unsigned int r = v.u + 0x7FFF + ((v.u >> 16) & 1);
    return (unsigned short)(r >> 16);
}

__device__ __forceinline__ void gload_lds16(const unsigned short* g, unsigned short* l) {
    __builtin_amdgcn_global_load_lds(
        (__attribute__((address_space(1))) void*)(g),
        (__attribute__((address_space(3))) void*)(l),
        16, 0, 0);
}

// XCD-chunked bijective swizzle for nwg=1280 (1280 % 8 == 0, chunk=160)
__device__ __forceinline__ int swz1280(int orig) {
    return (orig & 7) * 160 + (orig >> 3);
}

__device__ __forceinline__ f32x4 MF(short8 a, short8 b, f32x4 c) {
    return __builtin_amdgcn_mfma_f32_16x16x32_bf16(a, b, c, 0, 0, 0);
}

// ---------------------------------------------------------------------------
// ws layout (float offsets):
//   pool [0,464)  qwT [464,1488)  kw1T [1488,1616)  kw2T [1616,2640)
//   kw3T [2640,2768)
//   wbf  [122576,159440) : se_w1 bf16 [tap][mid=128][c=64]
//   w2bf [159440,161488) : se_w2 bf16 [j=32][mid=128]
//   wspf [161488,179920) : sp_w1 feat bf16 [tap][mid=64][c=64]
//   wspv [179920,189136) : sp_w1 vox/det bf16 [tap][mid=64][c=32]
//   featNHWC [189136, 10674896)  : [5][256][256][64] bf16, pos p holds ch p^((x&7)<<3)
//   vdNHWC   [10674896, 15917776): [5][256][256][32] bf16, pos p holds ch p^((x&3)<<3)
//   partials [15917776, 16036560): [464][256] per-(channel,y) row sums
// ---------------------------------------------------------------------------

__global__ __launch_bounds__(256) void k_transpose(
    const float* __restrict__ q_w, const float* __restrict__ k_w1,
    const float* __restrict__ k_w2, const float* __restrict__ k_w3,
    float* __restrict__ qwT, float* __restrict__ kw1T,
    float* __restrict__ kw2T, float* __restrict__ kw3T)
{
    int i = blockIdx.x * 256 + threadIdx.x;
    if (i < 1024)  { int o = i / 64,  c = i % 64;  qwT[c * 16 + o] = q_w[i];
                                                   kw2T[c * 16 + o] = k_w2[i]; }
    if (i < 128)   { int o = i / 8,   c = i % 8;   kw1T[c * 16 + o] = k_w1[i];
                                                   kw3T[c * 16 + o] = k_w3[i]; }
}

__global__ __launch_bounds__(256) void k_prep(
    const float* __restrict__ se_w1, const float* __restrict__ se_w2,
    const float* __restrict__ sp_w1,
    unsigned short* __restrict__ wbf, unsigned short* __restrict__ w2bf,
    unsigned short* __restrict__ wspf, unsigned short* __restrict__ wspv)
{
    int i = blockIdx.x * 256 + threadIdx.x;
    if (i < 73728) {
        int c = i & 63, mid = (i >> 6) & 127, tap = i >> 13;
        wbf[i] = f2bf(se_w1[(mid * 64 + c) * 9 + tap]);
    }
    if (i < 4096) w2bf[i] = f2bf(se_w2[i]);
    if (i < 36864) {
        int c = i & 63, mid = (i >> 6) & 63, tap = i >> 12;
        wspf[i] = f2bf(sp_w1[(mid * 80 + 8 + c) * 9 + tap]);
    }
    if (i < 18432) {
        int c = i & 31, mid = (i >> 5) & 63, tap = i >> 11;
        float v = 0.f;
        if (c < 8)       v = sp_w1[(mid * 80 + c) * 9 + tap];
        else if (c < 16) v = sp_w1[(mid * 80 + 64 + c) * 9 + tap];
        wspv[i] = f2bf(v);
    }
}

// ---------------------------------------------------------------------------
// NHWC prep: fp32 planes -> bf16 NHWC (pre-swizzled) + per-(channel,y) sums.
// ---------------------------------------------------------------------------
__global__ __launch_bounds__(256) void k_prep_nhwc(
    const float* __restrict__ ego_feat,
    const float* __restrict__ collab_vox, const float* __restrict__ collab_feat,
    const float* __restrict__ collab_det,
    unsigned short* __restrict__ featNHWC, unsigned short* __restrict__ vdNHWC,
    float* __restrict__ partials)
{
    __shared__ float lds_f[64 * 65];
    const int y = blockIdx.x, n = blockIdx.y;
    const int t = threadIdx.x;
    const bool ego = (n == 5);
    const float* featsrc = ego ? ego_feat : collab_feat + (size_t)n * 64 * HW;

    float psum = 0.f;
    const int c_ld = t >> 2, q0 = t & 3;
    for (int chunk = 0; chunk < 4; ++chunk) {
        const int x0c = chunk * 64;
        __syncthreads();
#pragma unroll
        for (int q = q0; q < 16; q += 4) {
            float4 v = *(const float4*)&featsrc[(size_t)c_ld * HW + y * 256 + x0c + q * 4];
            lds_f[c_ld * 65 + q * 4 + 0] = v.x;
            lds_f[c_ld * 65 + q * 4 + 1] = v.y;
            lds_f[c_ld * 65 + q * 4 + 2] = v.z;
            lds_f[c_ld * 65 + q * 4 + 3] = v.w;
            psum += (v.x + v.y) + (v.z + v.w);
        }
        __syncthreads();
        if (!ego) {
#pragma unroll
            for (int half = 0; half < 2; ++half) {
                int g = t & 7, xl = (t >> 3) + half * 32;
                int x = x0c + xl;
                int cg = g ^ (x & 7);
                unsigned short pk[8];
#pragma unroll
                for (int i = 0; i < 8; ++i)
                    pk[i] = f2bf(lds_f[(cg * 8 + i) * 65 + xl]);
                *(short8*)&featNHWC[(((size_t)n * 256 + y) * 256 + x) * 64 + g * 8] =
                    *(const short8*)pk;
            }
        }
    }
    psum += __shfl_xor(psum, 1, 64);
    psum += __shfl_xor(psum, 2, 64);
    if (q0 == 0) {
        int row = ego ? c_ld : 64 + n * 80 + 8 + c_ld;
        partials[row * 256 + y] = psum;
    }
    if (ego) return;

    float psv = 0.f;
    const int c2 = t >> 4, q2 = t & 15;
    const float* vdsrc = (c2 < 8) ? collab_vox + ((size_t)n * 8 + c2) * HW
                                  : collab_det + ((size_t)n * 8 + (c2 - 8)) * HW;
    for (int chunk = 0; chunk < 4; ++chunk) {
        const int x0c = chunk * 64;
        __syncthreads();
        {
            float4 v = *(const float4*)&vdsrc[y * 256 + x0c + q2 * 4];
            lds_f[c2 * 65 + q2 * 4 + 0] = v.x;
            lds_f[c2 * 65 + q2 * 4 + 1] = v.y;
            lds_f[c2 * 65 + q2 * 4 + 2] = v.z;
            lds_f[c2 * 65 + q2 * 4 + 3] = v.w;
            psv += (v.x + v.y) + (v.z + v.w);
        }
        __syncthreads();
        {
            int g = t & 3, xl = t >> 2;
            int x = x0c + xl;
            int cg = g ^ (x & 3);
            unsigned short pk[8];
#pragma unroll
            for (int i = 0; i < 8; ++i) {
                int cc = cg * 8 + i;
                pk[i] = (cc < 16) ? f2bf(lds_f[cc * 65 + xl]) : (unsigned short)0;
            }
            *(short8*)&vdNHWC[(((size_t)n * 256 + y) * 256 + x) * 32 + g * 8] =
                *(const short8*)pk;
        }
    }
    psv += __shfl_xor(psv, 1, 64);
    psv += __shfl_xor(psv, 2, 64);
    psv += __shfl_xor(psv, 4, 64);
    psv += __shfl_xor(psv, 8, 64);
    if (q2 == 0) {
        int row = 64 + n * 80 + (c2 < 8 ? c2 : c2 + 64);
        partials[row * 256 + y] = psv;
    }
}

__global__ __launch_bounds__(256) void k_pool2(
    const float* __restrict__ partials, float* __restrict__ pool)
{
    __shared__ float red[256];
    int r = blockIdx.x, t = threadIdx.x;
    red[t] = partials[r * 256 + t];
    __syncthreads();
    for (int s = 128; s > 0; s >>= 1) {
        if (t < s) red[t] += red[t + s];
        __syncthreads();
    }
    if (t == 0) pool[r] = red[0] * (1.f / HW);
}

// ---------------------------------------------------------------------------
// contribution + qk_attn : one thread per (agent, pixel)
// ---------------------------------------------------------------------------
__global__ __launch_bounds__(256) void k_contrib_qk(
    const float* __restrict__ ego_vox, const float* __restrict__ ego_feat,
    const float* __restrict__ ego_det,
    const float* __restrict__ collab_vox, const float* __restrict__ collab_feat,
    const float* __restrict__ collab_det,
    const float* __restrict__ qw, const float* __restrict__ kw1,
    const float* __restrict__ kw2, const float* __restrict__ kw3,
    float* __restrict__ out_contrib, float* __restrict__ out_qk)
{
    const int n = blockIdx.x >> 8;
    const int p = ((blockIdx.x & 255) << 8) | threadIdx.x;

    float q[16], k2[16];
#pragma unroll
    for (int o = 0; o < 16; o++) { q[o] = 0.f; k2[o] = 0.f; }
    float sq_ref = 0.f, dot_f = 0.f, sq_cf = 0.f;
#pragma unroll 4
    for (int c = 0; c < 64; c++) {
        float e = ego_feat[c * HW + p];
        float x = collab_feat[(n * 64 + c) * HW + p];
        sq_ref = fmaf(e, e, sq_ref);
        dot_f  = fmaf(x, e, dot_f);
        sq_cf  = fmaf(x, x, sq_cf);
#pragma unroll
        for (int o = 0; o < 16; o++) {
            q[o]  = fmaf(qw[c * 16 + o], e, q[o]);
            k2[o] = fmaf(kw2[c * 16 + o], x, k2[o]);
        }
    }
    float kx[16];
#pragma unroll
    for (int o = 0; o < 16; o++) kx[o] = 0.f;
    float dot_v = 0.f, sq_cv = 0.f;
#pragma unroll
    for (int c = 0; c < 8; c++) {
        float e = ego_vox[c * HW + p];
        float x = collab_vox[(n * 8 + c) * HW + p];
        sq_ref = fmaf(e, e, sq_ref);
        dot_v  = fmaf(x, e, dot_v);
        sq_cv  = fmaf(x, x, sq_cv);
#pragma unroll
        for (int o = 0; o < 16; o++)
            kx[o] = fmaf(kw1[c * 16 + o], x, kx[o]);
    }
    float s1 = 0.f;
#pragma unroll
    for (int o = 0; o < 16; o++) s1 = fmaf(q[o], kx[o], s1);
#pragma unroll
    for (int o = 0; o < 16; o++) kx[o] = 0.f;
    float dot_d = 0.f, sq_cd = 0.f;
#pragma unroll
    for (int c = 0; c < 8; c++) {
        float e = ego_det[c * HW + p];
        float x = collab_det[(n * 8 + c) * HW + p];
        sq_ref = fmaf(e, e, sq_ref);
        dot_d  = fmaf(x, e, dot_d);
        sq_cd  = fmaf(x, x, sq_cd);
#pragma unroll
        for (int o = 0; o < 16; o++)
            kx[o] = fmaf(kw3[c * 16 + o], x, kx[o]);
    }
    float s3 = 0.f, s2 = 0.f;
#pragma unroll
    for (int o = 0; o < 16; o++) { s3 = fmaf(q[o], kx[o], s3); s2 = fmaf(q[o], k2[o], s2); }

    float inv_ref = 1.f / fmaxf(sqrtf(sq_ref), EPSF);
    float simv = dot_v / fmaxf(sqrtf(sq_cv), EPSF) * inv_ref;
    float simf = dot_f / fmaxf(sqrtf(sq_cf), EPSF) * inv_ref;
    float simd_ = dot_d / fmaxf(sqrtf(sq_cd), EPSF) * inv_ref;
    out_contrib[(n * 3 + 0) * HW + p] = (simv + 1.f) * 0.5f;
    out_contrib[(n * 3 + 1) * HW + p] = (simf + 1.f) * 0.5f;
    out_contrib[(n * 3 + 2) * HW + p] = (simd_ + 1.f) * 0.5f;

    s1 *= 0.25f; s2 *= 0.25f; s3 *= 0.25f;
    float m = fmaxf(s1, fmaxf(s2, s3));
    float e1 = __expf(s1 - m), e2 = __expf(s2 - m), e3 = __expf(s3 - m);
    float inv = 1.f / (e1 + e2 + e3);
    out_qk[(n * 3 + 0) * HW + p] = e1 * inv;
    out_qk[(n * 3 + 1) * HW + p] = e2 * inv;
    out_qk[(n * 3 + 2) * HW + p] = e3 * inv;
}

// ---------------------------------------------------------------------------
__global__ __launch_bounds__(192) void k_mlps(
    const float* __restrict__ pool,
    const float* __restrict__ ch_w1, const float* __restrict__ ch_w2,
    const float* __restrict__ gr_w1, const float* __restrict__ gr_b1,
    const float* __restrict__ gr_w2, const float* __restrict__ gr_b2,
    float* __restrict__ out_gran, float* __restrict__ out_chan)
{
    __shared__ float h4[4], h32[5][32], logit[5][3];
    int t = threadIdx.x;
    if (t < 4) {
        float a = 0.f;
        for (int c = 0; c < 64; c++) a = fmaf(ch_w1[t * 64 + c], pool[c], a);
        h4[t] = fmaxf(a, 0.f);
    }
    if (t < 160) {
        int n = t >> 5, i = t & 31;
        float a = gr_b1[i];
        for (int c = 0; c < 80; c++) a = fmaf(gr_w1[i * 80 + c], pool[64 + n * 80 + c], a);
        h32[n][i] = fmaxf(a, 0.f);
    }
    __syncthreads();
    if (t < 64) {
        float m = 0.f;
#pragma unroll
        for (int j = 0; j < 4; j++) m = fmaf(ch_w2[t * 4 + j], h4[j], m);
        out_chan[t] = 1.f / (1.f + __expf(-2.f * m));
    }
    if (t < 15) {
        int n = t / 3, j = t % 3;
        float a = gr_b2[j];
#pragma unroll
        for (int i = 0; i < 32; i++) a = fmaf(gr_w2[j * 32 + i], h32[n][i], a);
        logit[n][j] = a;
    }
    __syncthreads();
    if (t < 5) {
        float a = logit[t][0], b = logit[t][1], c = logit[t][2];
        float m = fmaxf(a, fmaxf(b, c));
        float ea = __expf(a - m), eb = __expf(b - m), ec = __expf(c - m);
        float inv = 1.f / (ea + eb + ec);
        out_gran[t * 3 + 0] = ea * inv;
        out_gran[t * 3 + 1] = eb * inv;
        out_gran[t * 3 + 2] = ec * inv;
    }
}

// ---------------------------------------------------------------------------
// semantic attention v7: LDS = stage buffer only (50688 B) -> 3 blocks/CU
// via LDS limit, with (512,4) so the VGPR cap stays 128 (no spill — the R9
// lesson: (512,6) capped VGPRs at ~85 and spilled acc to scratch, 8x slower).
// GEMM2 runs in two 128-px halves overlaying the dead stage buffer.
// ---------------------------------------------------------------------------
__global__ __launch_bounds__(512, 4) void k_sem_nhwc(
    const unsigned short* __restrict__ featNHWC,
    const unsigned short* __restrict__ wbf,   // [9][128][64]
    const unsigned short* __restrict__ w2bf,  // [32][128]
    const float* __restrict__ se_b1, const float* __restrict__ se_b2,
    float* __restrict__ out_sem)
{
    __shared__ __align__(16) unsigned short smem[6 * 66 * 64];  // 50688 B
    const int bid = swz1280((int)blockIdx.x);
    const int n = bid >> 8, rem = bid & 255;
    const int x0 = (rem & 3) << 6, y0 = (rem >> 2) << 2;
    const int tid = threadIdx.x, lane = tid & 63, w = tid >> 6;
    const int wr = w >> 1, wc = w & 1;
    const int l15 = lane & 15, lg = lane >> 4;
    const short8 z8 = {0, 0, 0, 0, 0, 0, 0, 0};

    if (y0 == 0)
        for (int i = tid; i < 528; i += 512) *(short8*)&smem[i * 8] = z8;
    if (y0 == 252)
        for (int i = tid; i < 528; i += 512) *(short8*)&smem[5 * 66 * 64 + i * 8] = z8;

    for (int idx = w; idx < 48; idx += 8) {
        int dy = idx >> 3, k = idx & 7, gy = y0 - 1 + dy;
        if ((unsigned)gy < 256u)
            gload_lds16(
                &featNHWC[(((size_t)n * 256 + gy) * 256 + x0 + k * 8 + (lane >> 3)) * 64 + (lane & 7) * 8],
                &smem[(dy * 66 + 1 + k * 8) * 64]);
    }
    if (tid < 96) {
        int dy = tid >> 4, rem2 = tid & 15, side = rem2 >> 3, c8 = rem2 & 7;
        int gy = y0 - 1 + dy, gx = side ? x0 + 64 : x0 - 1, col = side ? 65 : 0;
        short8 v = z8;
        if ((unsigned)gy < 256u && (unsigned)gx < 256u)
            v = *(const short8*)&featNHWC[(((size_t)n * 256 + gy) * 256 + gx) * 64 + c8 * 8];
        *(short8*)&smem[(dy * 66 + col) * 64 + c8 * 8] = v;
    }
    __syncthreads();

    // ---- GEMM1: acc[mf][nf], pixel = mf*16+lg*4+rr in wave's row wr,
    //      mid = wc*64 + nf*16 + l15 ----
    const int midb = wc * 64 + l15;
    f32x4 acc[4][4] = {};
    short8 bc[4], bn[4];
#pragma unroll
    for (int nf = 0; nf < 4; ++nf)
        bc[nf] = *(const short8*)&wbf[(0 * 128 + midb + nf * 16) * 64 + lg * 8];

#pragma unroll 1
    for (int p = 0; p < 18; ++p) {
        const int tap = p >> 1, kc = p & 1;
        const int dyrow = tap / 3, dx = tap % 3;
        const int pn = (p < 17) ? p + 1 : 17;
        const int tapn = pn >> 1, kcn = pn & 1;
#pragma unroll
        for (int nf = 0; nf < 4; ++nf)
            bn[nf] = *(const short8*)&wbf[(tapn * 128 + midb + nf * 16) * 64 + kcn * 32 + lg * 8];
        const int c0 = kc * 32 + lg * 8;
        const int dyb = (wr + dyrow) * 66;
        short8 a[4];
#pragma unroll
        for (int mf = 0; mf < 4; ++mf) {
            int col = mf * 16 + l15 + dx;
            a[mf] = *(const short8*)&smem[(dyb + col) * 64 + (c0 ^ (((col + 7) & 7) << 3))];
        }
        __builtin_amdgcn_s_setprio(1);
#pragma unroll
        for (int mf = 0; mf < 4; ++mf)
#pragma unroll
            for (int nf = 0; nf < 4; ++nf)
                acc[mf][nf] = MF(a[mf], bc[nf], acc[mf][nf]);
        __builtin_amdgcn_s_setprio(0);
#pragma unroll
        for (int nf = 0; nf < 4; ++nf) bc[nf] = bn[nf];
    }
    __syncthreads();  // all waves done reading stage -> buffer reusable as P

    // ---- GEMM2 in two 128-px halves (rows {0,1} then {2,3}) ----
#pragma unroll 1
    for (int h = 0; h < 2; ++h) {
        // waves owning rows 2h, 2h+1 write their relu(mid+b1) into P[128][128]
        if ((wr >> 1) == h) {
            const int rbase = (wr & 1) * 64;
#pragma unroll
            for (int nf = 0; nf < 4; ++nf) {
                int mid = wc * 64 + nf * 16 + l15;
                float b1 = se_b1[mid];
#pragma unroll
                for (int mf = 0; mf < 4; ++mf) {
                    int mrow = rbase + mf * 16 + lg * 4;
#pragma unroll
                    for (int rr = 0; rr < 4; ++rr) {
                        int m = mrow + rr;
                        float v = fmaxf(acc[mf][nf][rr] + b1, 0.f);
                        smem[m * 128 + (mid ^ ((m & 7) << 3))] = f2bf(v);
                    }
                }
            }
        }
        __syncthreads();

        // all 8 waves: GEMM2 on P[128][128]; wave's m-chunk = w*16
        f32x4 acc2[2] = {};
        const int pxb = w * 16;
#pragma unroll
        for (int kc = 0; kc < 4; ++kc) {
            const int k0 = kc * 32 + lg * 8;
            int m = pxb + l15;
            short8 a2 = *(const short8*)&smem[m * 128 + (k0 ^ ((m & 7) << 3))];
            short8 b2[2];
#pragma unroll
            for (int nf = 0; nf < 2; ++nf) {
                int j = nf * 16 + l15;
                b2[nf] = *(const short8*)&w2bf[j * 128 + k0];
            }
#pragma unroll
            for (int nf = 0; nf < 2; ++nf)
                acc2[nf] = MF(a2, b2[nf], acc2[nf]);
        }
#pragma unroll
        for (int nf = 0; nf < 2; ++nf) {
            int j = nf * 16 + l15;
            float bj = se_b2[j];
            int m = pxb + lg * 4;           // D row (within half)
            int oy = h * 2 + (m >> 6), x = m & 63;
            float4 v;
            v.x = acc2[nf][0] + bj; v.y = acc2[nf][1] + bj;
            v.z = acc2[nf][2] + bj; v.w = acc2[nf][3] + bj;
            *(float4*)&out_sem[(size_t)(n * 32 + j) * HW + (y0 + oy) * 256 + x0 + x] = v;
        }
        if (h == 0) __syncthreads();  // before overwriting P with half 1
    }
}

// ---------------------------------------------------------------------------
// spatial attention v5 (unchanged from R7 — proven)
// ---------------------------------------------------------------------------
__global__ __launch_bounds__(512, 4) void k_spatial_nhwc(
    const unsigned short* __restrict__ featNHWC,
    const unsigned short* __restrict__ vdNHWC,
    const unsigned short* __restrict__ wspf,  // [9][64][64]
    const unsigned short* __restrict__ wspv,  // [9][64][32]
    const float* __restrict__ sp_b1, const float* __restrict__ sp_w2,
    const float* __restrict__ sp_b2,
    float* __restrict__ out_sp)
{
    __shared__ __align__(16) unsigned short sF[6 * 66 * 64];  // 50688 B
    __shared__ __align__(16) unsigned short sV[6 * 66 * 32];  // 25344 B
    const int bid = swz1280((int)blockIdx.x);
    const int n = bid >> 8, rem = bid & 255;
    const int x0 = (rem & 3) << 6, y0 = (rem >> 2) << 2;
    const int tid = threadIdx.x, lane = tid & 63, w = tid >> 6;
    const int l15 = lane & 15, lg = lane >> 4;
    const int wr = w >> 1, wc = w & 1;
    const short8 z8 = {0, 0, 0, 0, 0, 0, 0, 0};

    if (y0 == 0) {
        for (int i = tid; i < 528; i += 512) *(short8*)&sF[i * 8] = z8;
        for (int i = tid; i < 264; i += 512) *(short8*)&sV[i * 8] = z8;
    }
    if (y0 == 252) {
        for (int i = tid; i < 528; i += 512) *(short8*)&sF[5 * 66 * 64 + i * 8] = z8;
        for (int i = tid; i < 264; i += 512) *(short8*)&sV[5 * 66 * 32 + i * 8] = z8;
    }
    for (int idx = w; idx < 48; idx += 8) {
        int dy = idx >> 3, k = idx & 7, gy = y0 - 1 + dy;
        if ((unsigned)gy < 256u)
            gload_lds16(
                &featNHWC[(((size_t)n * 256 + gy) * 256 + x0 + k * 8 + (lane >> 3)) * 64 + (lane & 7) * 8],
                &sF[(dy * 66 + 1 + k * 8) * 64]);
    }
    for (int idx = w; idx < 24; idx += 8) {
        int dy = idx >> 2, k = idx & 3, gy = y0 - 1 + dy;
        if ((unsigned)gy < 256u)
            gload_lds16(
                &vdNHWC[(((size_t)n * 256 + gy) * 256 + x0 + k * 16 + (lane >> 2)) * 32 + (lane & 3) * 8],
                &sV[(dy * 66 + 1 + k * 16) * 32]);
    }
    if (tid < 96) {
        int dy = tid >> 4, rem2 = tid & 15, side = rem2 >> 3, c8 = rem2 & 7;
        int gy = y0 - 1 + dy, gx = side ? x0 + 64 : x0 - 1, col = side ? 65 : 0;
        short8 v = z8;
        if ((unsigned)gy < 256u && (unsigned)gx < 256u)
            v = *(const short8*)&featNHWC[(((size_t)n * 256 + gy) * 256 + gx) * 64 + c8 * 8];
        *(short8*)&sF[(dy * 66 + col) * 64 + c8 * 8] = v;
    } else if (tid < 144) {
        int t2 = tid - 96;
        int dy = t2 >> 3, rem2 = t2 & 7, side = rem2 >> 2, g4 = rem2 & 3;
        int gy = y0 - 1 + dy, gx = side ? x0 + 64 : x0 - 1, col = side ? 65 : 0;
        short8 v = z8;
        if ((unsigned)gy < 256u && (unsigned)gx < 256u)
            v = *(const short8*)&vdNHWC[(((size_t)n * 256 + gy) * 256 + gx) * 32 + g4 * 8];
        *(short8*)&sV[(dy * 66 + col) * 32 + g4 * 8] = v;
    }
    __syncthreads();

    f32x4 acc[4][2] = {};
    const int mid0 = wc * 32 + l15, mid1 = wc * 32 + 16 + l15;

    short8 bc0 = *(const short8*)&wspf[(0 * 64 + mid0) * 64 + lg * 8];
    short8 bc1 = *(const short8*)&wspf[(0 * 64 + mid1) * 64 + lg * 8];
#pragma unroll 1
    for (int p = 0; p < 18; ++p) {
        const int tap = p >> 1, kc = p & 1;
        const int dyrow = tap / 3, dx = tap % 3;
        const int pn = (p < 17) ? p + 1 : 17;
        const int tapn = pn >> 1, kcn = pn & 1;
        short8 bn0 = *(const short8*)&wspf[(tapn * 64 + mid0) * 64 + kcn * 32 + lg * 8];
        short8 bn1 = *(const short8*)&wspf[(tapn * 64 + mid1) * 64 + kcn * 32 + lg * 8];
        const int c0 = kc * 32 + lg * 8;
        const int dyb = (wr + dyrow) * 66;
        short8 a[4];
#pragma unroll
        for (int mf = 0; mf < 4; ++mf) {
            int col = mf * 16 + l15 + dx;
            a[mf] = *(const short8*)&sF[(dyb + col) * 64 + (c0 ^ (((col + 7) & 7) << 3))];
        }
        __builtin_amdgcn_s_setprio(1);
#pragma unroll
        for (int mf = 0; mf < 4; ++mf) {
            acc[mf][0] = MF(a[mf], bc0, acc[mf][0]);
            acc[mf][1] = MF(a[mf], bc1, acc[mf][1]);
        }
        __builtin_amdgcn_s_setprio(0);
        bc0 = bn0; bc1 = bn1;
    }

    const int c0v = lg * 8;
    short8 vc0 = *(const short8*)&wspv[(0 * 64 + mid0) * 32 + c0v];
    short8 vc1 = *(const short8*)&wspv[(0 * 64 + mid1) * 32 + c0v];
#pragma unroll 1
    for (int tap = 0; tap < 9; ++tap) {
        const int dyrow = tap / 3, dx = tap % 3;
        const int tapn = (tap < 8) ? tap + 1 : 8;
        short8 vn0 = *(const short8*)&wspv[(tapn * 64 + mid0) * 32 + c0v];
        short8 vn1 = *(const short8*)&wspv[(tapn * 64 + mid1) * 32 + c0v];
        const int dyb = (wr + dyrow) * 66;
        short8 a[4];
#pragma unroll
        for (int mf = 0; mf < 4; ++mf) {
            int col = mf * 16 + l15 + dx;
            a[mf] = *(const short8*)&sV[(dyb + col) * 32 + (c0v ^ (((col + 3) & 3) << 3))];
        }
        __builtin_amdgcn_s_setprio(1);
#pragma unroll
        for (int mf = 0; mf < 4; ++mf) {
            acc[mf][0] = MF(a[mf], vc0, acc[mf][0]);
            acc[mf][1] = MF(a[mf], vc1, acc[mf][1]);
        }
        __builtin_amdgcn_s_setprio(0);
        vc0 = vn0; vc1 = vn1;
    }

    const float w2v0 = sp_w2[mid0], w2v1 = sp_w2[mid1];
    const float b1v0 = sp_b1[mid0], b1v1 = sp_b1[mid1];
    float4 part[4];
#pragma unroll
    for (int mf = 0; mf < 4; ++mf) {
#pragma unroll
        for (int rr = 0; rr < 4; ++rr) {
            float s = fmaf(w2v0, fmaxf(acc[mf][0][rr] + b1v0, 0.f),
                           w2v1 * fmaxf(acc[mf][1][rr] + b1v1, 0.f));
            s += __shfl_xor(s, 1, 64);
            s += __shfl_xor(s, 2, 64);
            s += __shfl_xor(s, 4, 64);
            s += __shfl_xor(s, 8, 64);
            ((float*)&part[mf])[rr] = s;
        }
    }
    __syncthreads();
    float4* sP = (float4*)sV;
    if (wc == 1 && l15 == 0) {
#pragma unroll
        for (int mf = 0; mf < 4; ++mf) sP[(wr * 4 + mf) * 4 + lg] = part[mf];
    }
    __syncthreads();
    if (wc == 0 && l15 == 0) {
        const float b2 = sp_b2[0];
#pragma unroll
        for (int mf = 0; mf < 4; ++mf) {
            float4 o = sP[(wr * 4 + mf) * 4 + lg];
            float4 vout;
            vout.x = 1.f / (1.f + __expf(-(part[mf].x + o.x + b2)));
            vout.y = 1.f / (1.f + __expf(-(part[mf].y + o.y + b2)));
            vout.z = 1.f / (1.f + __expf(-(part[mf].z + o.z + b2)));
            vout.w = 1.f / (1.f + __expf(-(part[mf].w + o.w + b2)));
            *(float4*)&out_sp[(size_t)n * HW + (y0 + wr) * 256 + x0 + mf * 16 + lg * 4] = vout;
        }
    }
}

// ---------------------------------------------------------------------------
extern "C" void kernel_launch(void* const* d_in, const int* in_sizes, int n_in,
                              void* d_out, int out_size, void* d_ws, size_t ws_size,
                              hipStream_t stream)
{
    (void)in_sizes; (void)n_in; (void)out_size; (void)ws_size;
    const float* ego_vox     = (const float*)d_in[0];
    const float* ego_feat    = (const float*)d_in[1];
    const float* ego_det     = (const float*)d_in[2];
    const float* collab_vox  = (const float*)d_in[3];
    const float* collab_feat = (const float*)d_in[4];
    const float* collab_det  = (const float*)d_in[5];
    const float* q_w   = (const float*)d_in[6];
    const float* ch_w1 = (const float*)d_in[7];
    const float* ch_w2 = (const float*)d_in[8];
    const float* k_w1  = (const float*)d_in[9];
    const float* k_w2  = (const float*)d_in[10];
    const float* k_w3  = (const float*)d_in[11];
    const float* sp_w1 = (const float*)d_in[12];
    const float* sp_b1 = (const float*)d_in[13];
    const float* sp_w2 = (const float*)d_in[14];
    const float* sp_b2 = (const float*)d_in[15];
    const float* gr_w1 = (const float*)d_in[16];
    const float* gr_b1 = (const float*)d_in[17];
    const float* gr_w2 = (const float*)d_in[18];
    const float* gr_b2 = (const float*)d_in[19];
    const float* se_w1 = (const float*)d_in[20];
    const float* se_b1 = (const float*)d_in[21];
    const float* se_w2 = (const float*)d_in[22];
    const float* se_b2 = (const float*)d_in[23];

    float* out = (float*)d_out;
    float* o_contrib = out;                 // [5,3,256,256]
    float* o_qk      = out + 983040;        // [5,3,256,256]
    float* o_sp      = out + 1966080;       // [5,1,256,256]
    float* o_gran    = out + 2293760;       // [5,3]
    float* o_sem     = out + 2293775;       // [5,32,256,256]
    float* o_chan    = out + 12779535;      // [64]

    float* wsf  = (float*)d_ws;
    float* pool = wsf;
    float* qwT  = wsf + 464;
    float* kw1T = wsf + 1488;
    float* kw2T = wsf + 1616;
    float* kw3T = wsf + 2640;
    unsigned short* wbf  = (unsigned short*)(wsf + 122576);
    unsigned short* w2bf = (unsigned short*)(wsf + 159440);
    unsigned short* wspf = (unsigned short*)(wsf + 161488);
    unsigned short* wspv = (unsigned short*)(wsf + 179920);
    unsigned short* featNHWC = (unsigned short*)(wsf + 189136);
    unsigned short* vdNHWC   = (unsigned short*)(wsf + 10674896);
    float* partials          = wsf + 15917776;

    k_prep<<<288, 256, 0, stream>>>(se_w1, se_w2, sp_w1, wbf, w2bf, wspf, wspv);
    k_transpose<<<4, 256, 0, stream>>>(q_w, k_w1, k_w2, k_w3, qwT, kw1T, kw2T, kw3T);

    k_contrib_qk<<<1280, 256, 0, stream>>>(
        ego_vox, ego_feat, ego_det, collab_vox, collab_feat, collab_det,
        qwT, kw1T, kw2T, kw3T, o_contrib, o_qk);

    k_prep_nhwc<<<dim3(256, 6), 256, 0, stream>>>(
        ego_feat, collab_vox, collab_feat, collab_det,
        featNHWC, vdNHWC, partials);
    k_pool2<<<464, 256, 0, stream>>>(partials, pool);
    k_mlps<<<1, 192, 0, stream>>>(pool, ch_w1, ch_w2, gr_w1, gr_b1, gr_w2, gr_b2,
                                  o_gran, o_chan);

    k_spatial_nhwc<<<1280, 512, 0, stream>>>(
        featNHWC, vdNHWC, wspf, wspv, sp_b1, sp_w2, sp_b2, o_sp);
    k_sem_nhwc<<<1280, 512, 0, stream>>>(
        featNHWC, wbf, w2bf, se_b1, se_b2, o_sem);
}

// Round 11
// 252.196 us; speedup vs baseline: 3.8595x; 1.3839x over previous
//
#include <hip/hip_runtime.h>
#include <math.h>

#define HW 65536
#define NAG 5
#define EPSF 1e-8f

typedef __attribute__((ext_vector_type(8))) short short8;
typedef __attribute__((ext_vector_type(4))) float f32x4;

__device__ __forceinline__ unsigned short f2bf(float f) {
    union { float f; unsigned int u; } v; v.f = f;
    unsigned int r = v.u + 0x7FFF + ((v.u >> 16) & 1);
    return (unsigned short)(r >> 16);
}

__device__ __forceinline__ void gload_lds16(const unsigned short* g, unsigned short* l) {
    __builtin_amdgcn_global_load_lds(
        (__attribute__((address_space(1))) void*)(g),
        (__attribute__((address_space(3))) void*)(l),
        16, 0, 0);
}

// XCD-chunked bijective swizzle (nwg % 8 == 0)
__device__ __forceinline__ int swz1280(int orig) {
    return (orig & 7) * 160 + (orig >> 3);
}
__device__ __forceinline__ int swz2560(int orig) {
    return (orig & 7) * 320 + (orig >> 3);
}

__device__ __forceinline__ f32x4 MF(short8 a, short8 b, f32x4 c) {
    return __builtin_amdgcn_mfma_f32_16x16x32_bf16(a, b, c, 0, 0, 0);
}

// ---------------------------------------------------------------------------
// ws layout (float offsets):
//   pool [0,464)  qwT [464,1488)  kw1T [1488,1616)  kw2T [1616,2640)
//   kw3T [2640,2768)
//   wbf  [122576,159440) : se_w1 bf16 [tap][mid=128][c=64]
//   w2bf [159440,161488) : se_w2 bf16 [j=32][mid=128]
//   wspf [161488,179920) : sp_w1 feat bf16 [tap][mid=64][c=64]
//   wspv [179920,189136) : sp_w1 vox/det bf16 [tap][mid=64][c=32]
//   featNHWC [189136, 10674896)  : [5][256][256][64] bf16, pos p holds ch p^((x&7)<<3)
//   vdNHWC   [10674896, 15917776): [5][256][256][32] bf16, pos p holds ch p^((x&3)<<3)
//   partials [15917776, 16036560): [464][256] per-(channel,y) row sums
// ---------------------------------------------------------------------------

__global__ __launch_bounds__(256) void k_transpose(
    const float* __restrict__ q_w, const float* __restrict__ k_w1,
    const float* __restrict__ k_w2, const float* __restrict__ k_w3,
    float* __restrict__ qwT, float* __restrict__ kw1T,
    float* __restrict__ kw2T, float* __restrict__ kw3T)
{
    int i = blockIdx.x * 256 + threadIdx.x;
    if (i < 1024)  { int o = i / 64,  c = i % 64;  qwT[c * 16 + o] = q_w[i];
                                                   kw2T[c * 16 + o] = k_w2[i]; }
    if (i < 128)   { int o = i / 8,   c = i % 8;   kw1T[c * 16 + o] = k_w1[i];
                                                   kw3T[c * 16 + o] = k_w3[i]; }
}

__global__ __launch_bounds__(256) void k_prep(
    const float* __restrict__ se_w1, const float* __restrict__ se_w2,
    const float* __restrict__ sp_w1,
    unsigned short* __restrict__ wbf, unsigned short* __restrict__ w2bf,
    unsigned short* __restrict__ wspf, unsigned short* __restrict__ wspv)
{
    int i = blockIdx.x * 256 + threadIdx.x;
    if (i < 73728) {
        int c = i & 63, mid = (i >> 6) & 127, tap = i >> 13;
        wbf[i] = f2bf(se_w1[(mid * 64 + c) * 9 + tap]);
    }
    if (i < 4096) w2bf[i] = f2bf(se_w2[i]);
    if (i < 36864) {
        int c = i & 63, mid = (i >> 6) & 63, tap = i >> 12;
        wspf[i] = f2bf(sp_w1[(mid * 80 + 8 + c) * 9 + tap]);
    }
    if (i < 18432) {
        int c = i & 31, mid = (i >> 5) & 63, tap = i >> 11;
        float v = 0.f;
        if (c < 8)       v = sp_w1[(mid * 80 + c) * 9 + tap];
        else if (c < 16) v = sp_w1[(mid * 80 + 64 + c) * 9 + tap];
        wspv[i] = f2bf(v);
    }
}

// ---------------------------------------------------------------------------
// NHWC prep: fp32 planes -> bf16 NHWC (pre-swizzled) + per-(channel,y) sums.
// ---------------------------------------------------------------------------
__global__ __launch_bounds__(256) void k_prep_nhwc(
    const float* __restrict__ ego_feat,
    const float* __restrict__ collab_vox, const float* __restrict__ collab_feat,
    const float* __restrict__ collab_det,
    unsigned short* __restrict__ featNHWC, unsigned short* __restrict__ vdNHWC,
    float* __restrict__ partials)
{
    __shared__ float lds_f[64 * 65];
    const int y = blockIdx.x, n = blockIdx.y;
    const int t = threadIdx.x;
    const bool ego = (n == 5);
    const float* featsrc = ego ? ego_feat : collab_feat + (size_t)n * 64 * HW;

    float psum = 0.f;
    const int c_ld = t >> 2, q0 = t & 3;
    for (int chunk = 0; chunk < 4; ++chunk) {
        const int x0c = chunk * 64;
        __syncthreads();
#pragma unroll
        for (int q = q0; q < 16; q += 4) {
            float4 v = *(const float4*)&featsrc[(size_t)c_ld * HW + y * 256 + x0c + q * 4];
            lds_f[c_ld * 65 + q * 4 + 0] = v.x;
            lds_f[c_ld * 65 + q * 4 + 1] = v.y;
            lds_f[c_ld * 65 + q * 4 + 2] = v.z;
            lds_f[c_ld * 65 + q * 4 + 3] = v.w;
            psum += (v.x + v.y) + (v.z + v.w);
        }
        __syncthreads();
        if (!ego) {
#pragma unroll
            for (int half = 0; half < 2; ++half) {
                int g = t & 7, xl = (t >> 3) + half * 32;
                int x = x0c + xl;
                int cg = g ^ (x & 7);
                unsigned short pk[8];
#pragma unroll
                for (int i = 0; i < 8; ++i)
                    pk[i] = f2bf(lds_f[(cg * 8 + i) * 65 + xl]);
                *(short8*)&featNHWC[(((size_t)n * 256 + y) * 256 + x) * 64 + g * 8] =
                    *(const short8*)pk;
            }
        }
    }
    psum += __shfl_xor(psum, 1, 64);
    psum += __shfl_xor(psum, 2, 64);
    if (q0 == 0) {
        int row = ego ? c_ld : 64 + n * 80 + 8 + c_ld;
        partials[row * 256 + y] = psum;
    }
    if (ego) return;

    float psv = 0.f;
    const int c2 = t >> 4, q2 = t & 15;
    const float* vdsrc = (c2 < 8) ? collab_vox + ((size_t)n * 8 + c2) * HW
                                  : collab_det + ((size_t)n * 8 + (c2 - 8)) * HW;
    for (int chunk = 0; chunk < 4; ++chunk) {
        const int x0c = chunk * 64;
        __syncthreads();
        {
            float4 v = *(const float4*)&vdsrc[y * 256 + x0c + q2 * 4];
            lds_f[c2 * 65 + q2 * 4 + 0] = v.x;
            lds_f[c2 * 65 + q2 * 4 + 1] = v.y;
            lds_f[c2 * 65 + q2 * 4 + 2] = v.z;
            lds_f[c2 * 65 + q2 * 4 + 3] = v.w;
            psv += (v.x + v.y) + (v.z + v.w);
        }
        __syncthreads();
        {
            int g = t & 3, xl = t >> 2;
            int x = x0c + xl;
            int cg = g ^ (x & 3);
            unsigned short pk[8];
#pragma unroll
            for (int i = 0; i < 8; ++i) {
                int cc = cg * 8 + i;
                pk[i] = (cc < 16) ? f2bf(lds_f[cc * 65 + xl]) : (unsigned short)0;
            }
            *(short8*)&vdNHWC[(((size_t)n * 256 + y) * 256 + x) * 32 + g * 8] =
                *(const short8*)pk;
        }
    }
    psv += __shfl_xor(psv, 1, 64);
    psv += __shfl_xor(psv, 2, 64);
    psv += __shfl_xor(psv, 4, 64);
    psv += __shfl_xor(psv, 8, 64);
    if (q2 == 0) {
        int row = 64 + n * 80 + (c2 < 8 ? c2 : c2 + 64);
        partials[row * 256 + y] = psv;
    }
}

__global__ __launch_bounds__(256) void k_pool2(
    const float* __restrict__ partials, float* __restrict__ pool)
{
    __shared__ float red[256];
    int r = blockIdx.x, t = threadIdx.x;
    red[t] = partials[r * 256 + t];
    __syncthreads();
    for (int s = 128; s > 0; s >>= 1) {
        if (t < s) red[t] += red[t + s];
        __syncthreads();
    }
    if (t == 0) pool[r] = red[0] * (1.f / HW);
}

// ---------------------------------------------------------------------------
// contribution + qk_attn : one thread per (agent, pixel)
// ---------------------------------------------------------------------------
__global__ __launch_bounds__(256) void k_contrib_qk(
    const float* __restrict__ ego_vox, const float* __restrict__ ego_feat,
    const float* __restrict__ ego_det,
    const float* __restrict__ collab_vox, const float* __restrict__ collab_feat,
    const float* __restrict__ collab_det,
    const float* __restrict__ qw, const float* __restrict__ kw1,
    const float* __restrict__ kw2, const float* __restrict__ kw3,
    float* __restrict__ out_contrib, float* __restrict__ out_qk)
{
    const int n = blockIdx.x >> 8;
    const int p = ((blockIdx.x & 255) << 8) | threadIdx.x;

    float q[16], k2[16];
#pragma unroll
    for (int o = 0; o < 16; o++) { q[o] = 0.f; k2[o] = 0.f; }
    float sq_ref = 0.f, dot_f = 0.f, sq_cf = 0.f;
#pragma unroll 4
    for (int c = 0; c < 64; c++) {
        float e = ego_feat[c * HW + p];
        float x = collab_feat[(n * 64 + c) * HW + p];
        sq_ref = fmaf(e, e, sq_ref);
        dot_f  = fmaf(x, e, dot_f);
        sq_cf  = fmaf(x, x, sq_cf);
#pragma unroll
        for (int o = 0; o < 16; o++) {
            q[o]  = fmaf(qw[c * 16 + o], e, q[o]);
            k2[o] = fmaf(kw2[c * 16 + o], x, k2[o]);
        }
    }
    float kx[16];
#pragma unroll
    for (int o = 0; o < 16; o++) kx[o] = 0.f;
    float dot_v = 0.f, sq_cv = 0.f;
#pragma unroll
    for (int c = 0; c < 8; c++) {
        float e = ego_vox[c * HW + p];
        float x = collab_vox[(n * 8 + c) * HW + p];
        sq_ref = fmaf(e, e, sq_ref);
        dot_v  = fmaf(x, e, dot_v);
        sq_cv  = fmaf(x, x, sq_cv);
#pragma unroll
        for (int o = 0; o < 16; o++)
            kx[o] = fmaf(kw1[c * 16 + o], x, kx[o]);
    }
    float s1 = 0.f;
#pragma unroll
    for (int o = 0; o < 16; o++) s1 = fmaf(q[o], kx[o], s1);
#pragma unroll
    for (int o = 0; o < 16; o++) kx[o] = 0.f;
    float dot_d = 0.f, sq_cd = 0.f;
#pragma unroll
    for (int c = 0; c < 8; c++) {
        float e = ego_det[c * HW + p];
        float x = collab_det[(n * 8 + c) * HW + p];
        sq_ref = fmaf(e, e, sq_ref);
        dot_d  = fmaf(x, e, dot_d);
        sq_cd  = fmaf(x, x, sq_cd);
#pragma unroll
        for (int o = 0; o < 16; o++)
            kx[o] = fmaf(kw3[c * 16 + o], x, kx[o]);
    }
    float s3 = 0.f, s2 = 0.f;
#pragma unroll
    for (int o = 0; o < 16; o++) { s3 = fmaf(q[o], kx[o], s3); s2 = fmaf(q[o], k2[o], s2); }

    float inv_ref = 1.f / fmaxf(sqrtf(sq_ref), EPSF);
    float simv = dot_v / fmaxf(sqrtf(sq_cv), EPSF) * inv_ref;
    float simf = dot_f / fmaxf(sqrtf(sq_cf), EPSF) * inv_ref;
    float simd_ = dot_d / fmaxf(sqrtf(sq_cd), EPSF) * inv_ref;
    out_contrib[(n * 3 + 0) * HW + p] = (simv + 1.f) * 0.5f;
    out_contrib[(n * 3 + 1) * HW + p] = (simf + 1.f) * 0.5f;
    out_contrib[(n * 3 + 2) * HW + p] = (simd_ + 1.f) * 0.5f;

    s1 *= 0.25f; s2 *= 0.25f; s3 *= 0.25f;
    float m = fmaxf(s1, fmaxf(s2, s3));
    float e1 = __expf(s1 - m), e2 = __expf(s2 - m), e3 = __expf(s3 - m);
    float inv = 1.f / (e1 + e2 + e3);
    out_qk[(n * 3 + 0) * HW + p] = e1 * inv;
    out_qk[(n * 3 + 1) * HW + p] = e2 * inv;
    out_qk[(n * 3 + 2) * HW + p] = e3 * inv;
}

// ---------------------------------------------------------------------------
__global__ __launch_bounds__(192) void k_mlps(
    const float* __restrict__ pool,
    const float* __restrict__ ch_w1, const float* __restrict__ ch_w2,
    const float* __restrict__ gr_w1, const float* __restrict__ gr_b1,
    const float* __restrict__ gr_w2, const float* __restrict__ gr_b2,
    float* __restrict__ out_gran, float* __restrict__ out_chan)
{
    __shared__ float h4[4], h32[5][32], logit[5][3];
    int t = threadIdx.x;
    if (t < 4) {
        float a = 0.f;
        for (int c = 0; c < 64; c++) a = fmaf(ch_w1[t * 64 + c], pool[c], a);
        h4[t] = fmaxf(a, 0.f);
    }
    if (t < 160) {
        int n = t >> 5, i = t & 31;
        float a = gr_b1[i];
        for (int c = 0; c < 80; c++) a = fmaf(gr_w1[i * 80 + c], pool[64 + n * 80 + c], a);
        h32[n][i] = fmaxf(a, 0.f);
    }
    __syncthreads();
    if (t < 64) {
        float m = 0.f;
#pragma unroll
        for (int j = 0; j < 4; j++) m = fmaf(ch_w2[t * 4 + j], h4[j], m);
        out_chan[t] = 1.f / (1.f + __expf(-2.f * m));
    }
    if (t < 15) {
        int n = t / 3, j = t % 3;
        float a = gr_b2[j];
#pragma unroll
        for (int i = 0; i < 32; i++) a = fmaf(gr_w2[j * 32 + i], h32[n][i], a);
        logit[n][j] = a;
    }
    __syncthreads();
    if (t < 5) {
        float a = logit[t][0], b = logit[t][1], c = logit[t][2];
        float m = fmaxf(a, fmaxf(b, c));
        float ea = __expf(a - m), eb = __expf(b - m), ec = __expf(c - m);
        float inv = 1.f / (ea + eb + ec);
        out_gran[t * 3 + 0] = ea * inv;
        out_gran[t * 3 + 1] = eb * inv;
        out_gran[t * 3 + 2] = ec * inv;
    }
}

// ---------------------------------------------------------------------------
// semantic attention v8: 256 threads (4 waves), tile = 2 rows x 64 cols.
// Stage [4][66][64] = 33792 B; P[128][128] = 32768 B fully overlays it ->
// single-pass GEMM2 (acc consumed at ONE point, the R9/R10 spill lesson).
// LDS 33 KB -> 4 blocks/CU: more independent barrier domains.
// ---------------------------------------------------------------------------
__global__ __launch_bounds__(256, 4) void k_sem_nhwc(
    const unsigned short* __restrict__ featNHWC,
    const unsigned short* __restrict__ wbf,   // [9][128][64]
    const unsigned short* __restrict__ w2bf,  // [32][128]
    const float* __restrict__ se_b1, const float* __restrict__ se_b2,
    float* __restrict__ out_sem)
{
    __shared__ __align__(16) unsigned short smem[4 * 66 * 64];  // 33792 B
    const int bid = swz2560((int)blockIdx.x);
    const int n = bid >> 9, rem = bid & 511;       // 512 tiles per n: 128y x 4x
    const int x0 = (rem & 3) << 6, y0 = (rem >> 2) << 1;
    const int tid = threadIdx.x, lane = tid & 63, w = tid >> 6;  // w 0..3
    const int wr = w >> 1, wc = w & 1;
    const int l15 = lane & 15, lg = lane >> 4;
    const short8 z8 = {0, 0, 0, 0, 0, 0, 0, 0};

    if (y0 == 0)
        for (int i = tid; i < 528; i += 256) *(short8*)&smem[i * 8] = z8;
    if (y0 == 254)
        for (int i = tid; i < 528; i += 256) *(short8*)&smem[3 * 66 * 64 + i * 8] = z8;

    // interior: 4 rows x 8 chunks = 32 DMA loads, 8 per wave
    for (int idx = w; idx < 32; idx += 4) {
        int dy = idx >> 3, k = idx & 7, gy = y0 - 1 + dy;
        if ((unsigned)gy < 256u)
            gload_lds16(
                &featNHWC[(((size_t)n * 256 + gy) * 256 + x0 + k * 8 + (lane >> 3)) * 64 + (lane & 7) * 8],
                &smem[(dy * 66 + 1 + k * 8) * 64]);
    }
    // halo cols
    if (tid < 64) {
        int dy = tid >> 4, rem2 = tid & 15, side = rem2 >> 3, c8 = rem2 & 7;
        int gy = y0 - 1 + dy, gx = side ? x0 + 64 : x0 - 1, col = side ? 65 : 0;
        short8 v = z8;
        if ((unsigned)gy < 256u && (unsigned)gx < 256u)
            v = *(const short8*)&featNHWC[(((size_t)n * 256 + gy) * 256 + gx) * 64 + c8 * 8];
        *(short8*)&smem[(dy * 66 + col) * 64 + c8 * 8] = v;
    }
    __syncthreads();

    // ---- GEMM1: wave (wr,wc) -> row wr (64 px), mids wc*64..+63 ----
    const int midb = wc * 64 + l15;
    f32x4 acc[4][4] = {};
    short8 bc[4], bn[4];
#pragma unroll
    for (int nf = 0; nf < 4; ++nf)
        bc[nf] = *(const short8*)&wbf[(0 * 128 + midb + nf * 16) * 64 + lg * 8];

#pragma unroll 1
    for (int p = 0; p < 18; ++p) {
        const int tap = p >> 1, kc = p & 1;
        const int dyrow = tap / 3, dx = tap % 3;
        const int pn = (p < 17) ? p + 1 : 17;
        const int tapn = pn >> 1, kcn = pn & 1;
#pragma unroll
        for (int nf = 0; nf < 4; ++nf)
            bn[nf] = *(const short8*)&wbf[(tapn * 128 + midb + nf * 16) * 64 + kcn * 32 + lg * 8];
        const int c0 = kc * 32 + lg * 8;
        const int dyb = (wr + dyrow) * 66;
        short8 a[4];
#pragma unroll
        for (int mf = 0; mf < 4; ++mf) {
            int col = mf * 16 + l15 + dx;
            a[mf] = *(const short8*)&smem[(dyb + col) * 64 + (c0 ^ (((col + 7) & 7) << 3))];
        }
        __builtin_amdgcn_s_setprio(1);
#pragma unroll
        for (int mf = 0; mf < 4; ++mf)
#pragma unroll
            for (int nf = 0; nf < 4; ++nf)
                acc[mf][nf] = MF(a[mf], bc[nf], acc[mf][nf]);
        __builtin_amdgcn_s_setprio(0);
#pragma unroll
        for (int nf = 0; nf < 4; ++nf) bc[nf] = bn[nf];
    }
    __syncthreads();  // all waves done reading stage -> buffer reusable as P

    // ---- P write: relu(mid+b1) -> P[m][mid ^ ((m&7)<<3)], m = wr*64 + ... ----
#pragma unroll
    for (int nf = 0; nf < 4; ++nf) {
        int mid = wc * 64 + nf * 16 + l15;
        float b1 = se_b1[mid];
#pragma unroll
        for (int mf = 0; mf < 4; ++mf) {
            int mrow = wr * 64 + mf * 16 + lg * 4;
#pragma unroll
            for (int rr = 0; rr < 4; ++rr) {
                int m = mrow + rr;
                float v = fmaxf(acc[mf][nf][rr] + b1, 0.f);
                smem[m * 128 + (mid ^ ((m & 7) << 3))] = f2bf(v);
            }
        }
    }
    __syncthreads();

    // ---- GEMM2: 4 waves x 32 px each, K = 128 ----
    f32x4 acc2[2][2] = {};
    const int pxb = w * 32;
#pragma unroll
    for (int kc = 0; kc < 4; ++kc) {
        const int k0 = kc * 32 + lg * 8;
        short8 a2[2], b2[2];
#pragma unroll
        for (int mf = 0; mf < 2; ++mf) {
            int m = pxb + mf * 16 + l15;
            a2[mf] = *(const short8*)&smem[m * 128 + (k0 ^ ((m & 7) << 3))];
        }
#pragma unroll
        for (int nf = 0; nf < 2; ++nf) {
            int j = nf * 16 + l15;
            b2[nf] = *(const short8*)&w2bf[j * 128 + k0];
        }
#pragma unroll
        for (int mf = 0; mf < 2; ++mf)
#pragma unroll
            for (int nf = 0; nf < 2; ++nf)
                acc2[mf][nf] = MF(a2[mf], b2[nf], acc2[mf][nf]);
    }
#pragma unroll
    for (int nf = 0; nf < 2; ++nf) {
        int j = nf * 16 + l15;
        float bj = se_b2[j];
#pragma unroll
        for (int mf = 0; mf < 2; ++mf) {
            int m = pxb + mf * 16 + lg * 4;   // 0..127
            int oy = m >> 6, x = m & 63;
            float4 v;
            v.x = acc2[mf][nf][0] + bj; v.y = acc2[mf][nf][1] + bj;
            v.z = acc2[mf][nf][2] + bj; v.w = acc2[mf][nf][3] + bj;
            *(float4*)&out_sem[(size_t)(n * 32 + j) * HW + (y0 + oy) * 256 + x0 + x] = v;
        }
    }
}

// ---------------------------------------------------------------------------
// spatial attention v5 (unchanged from R7 — proven)
// ---------------------------------------------------------------------------
__global__ __launch_bounds__(512, 4) void k_spatial_nhwc(
    const unsigned short* __restrict__ featNHWC,
    const unsigned short* __restrict__ vdNHWC,
    const unsigned short* __restrict__ wspf,  // [9][64][64]
    const unsigned short* __restrict__ wspv,  // [9][64][32]
    const float* __restrict__ sp_b1, const float* __restrict__ sp_w2,
    const float* __restrict__ sp_b2,
    float* __restrict__ out_sp)
{
    __shared__ __align__(16) unsigned short sF[6 * 66 * 64];  // 50688 B
    __shared__ __align__(16) unsigned short sV[6 * 66 * 32];  // 25344 B
    const int bid = swz1280((int)blockIdx.x);
    const int n = bid >> 8, rem = bid & 255;
    const int x0 = (rem & 3) << 6, y0 = (rem >> 2) << 2;
    const int tid = threadIdx.x, lane = tid & 63, w = tid >> 6;
    const int l15 = lane & 15, lg = lane >> 4;
    const int wr = w >> 1, wc = w & 1;
    const short8 z8 = {0, 0, 0, 0, 0, 0, 0, 0};

    if (y0 == 0) {
        for (int i = tid; i < 528; i += 512) *(short8*)&sF[i * 8] = z8;
        for (int i = tid; i < 264; i += 512) *(short8*)&sV[i * 8] = z8;
    }
    if (y0 == 252) {
        for (int i = tid; i < 528; i += 512) *(short8*)&sF[5 * 66 * 64 + i * 8] = z8;
        for (int i = tid; i < 264; i += 512) *(short8*)&sV[5 * 66 * 32 + i * 8] = z8;
    }
    for (int idx = w; idx < 48; idx += 8) {
        int dy = idx >> 3, k = idx & 7, gy = y0 - 1 + dy;
        if ((unsigned)gy < 256u)
            gload_lds16(
                &featNHWC[(((size_t)n * 256 + gy) * 256 + x0 + k * 8 + (lane >> 3)) * 64 + (lane & 7) * 8],
                &sF[(dy * 66 + 1 + k * 8) * 64]);
    }
    for (int idx = w; idx < 24; idx += 8) {
        int dy = idx >> 2, k = idx & 3, gy = y0 - 1 + dy;
        if ((unsigned)gy < 256u)
            gload_lds16(
                &vdNHWC[(((size_t)n * 256 + gy) * 256 + x0 + k * 16 + (lane >> 2)) * 32 + (lane & 3) * 8],
                &sV[(dy * 66 + 1 + k * 16) * 32]);
    }
    if (tid < 96) {
        int dy = tid >> 4, rem2 = tid & 15, side = rem2 >> 3, c8 = rem2 & 7;
        int gy = y0 - 1 + dy, gx = side ? x0 + 64 : x0 - 1, col = side ? 65 : 0;
        short8 v = z8;
        if ((unsigned)gy < 256u && (unsigned)gx < 256u)
            v = *(const short8*)&featNHWC[(((size_t)n * 256 + gy) * 256 + gx) * 64 + c8 * 8];
        *(short8*)&sF[(dy * 66 + col) * 64 + c8 * 8] = v;
    } else if (tid < 144) {
        int t2 = tid - 96;
        int dy = t2 >> 3, rem2 = t2 & 7, side = rem2 >> 2, g4 = rem2 & 3;
        int gy = y0 - 1 + dy, gx = side ? x0 + 64 : x0 - 1, col = side ? 65 : 0;
        short8 v = z8;
        if ((unsigned)gy < 256u && (unsigned)gx < 256u)
            v = *(const short8*)&vdNHWC[(((size_t)n * 256 + gy) * 256 + gx) * 32 + g4 * 8];
        *(short8*)&sV[(dy * 66 + col) * 32 + g4 * 8] = v;
    }
    __syncthreads();

    f32x4 acc[4][2] = {};
    const int mid0 = wc * 32 + l15, mid1 = wc * 32 + 16 + l15;

    short8 bc0 = *(const short8*)&wspf[(0 * 64 + mid0) * 64 + lg * 8];
    short8 bc1 = *(const short8*)&wspf[(0 * 64 + mid1) * 64 + lg * 8];
#pragma unroll 1
    for (int p = 0; p < 18; ++p) {
        const int tap = p >> 1, kc = p & 1;
        const int dyrow = tap / 3, dx = tap % 3;
        const int pn = (p < 17) ? p + 1 : 17;
        const int tapn = pn >> 1, kcn = pn & 1;
        short8 bn0 = *(const short8*)&wspf[(tapn * 64 + mid0) * 64 + kcn * 32 + lg * 8];
        short8 bn1 = *(const short8*)&wspf[(tapn * 64 + mid1) * 64 + kcn * 32 + lg * 8];
        const int c0 = kc * 32 + lg * 8;
        const int dyb = (wr + dyrow) * 66;
        short8 a[4];
#pragma unroll
        for (int mf = 0; mf < 4; ++mf) {
            int col = mf * 16 + l15 + dx;
            a[mf] = *(const short8*)&sF[(dyb + col) * 64 + (c0 ^ (((col + 7) & 7) << 3))];
        }
        __builtin_amdgcn_s_setprio(1);
#pragma unroll
        for (int mf = 0; mf < 4; ++mf) {
            acc[mf][0] = MF(a[mf], bc0, acc[mf][0]);
            acc[mf][1] = MF(a[mf], bc1, acc[mf][1]);
        }
        __builtin_amdgcn_s_setprio(0);
        bc0 = bn0; bc1 = bn1;
    }

    const int c0v = lg * 8;
    short8 vc0 = *(const short8*)&wspv[(0 * 64 + mid0) * 32 + c0v];
    short8 vc1 = *(const short8*)&wspv[(0 * 64 + mid1) * 32 + c0v];
#pragma unroll 1
    for (int tap = 0; tap < 9; ++tap) {
        const int dyrow = tap / 3, dx = tap % 3;
        const int tapn = (tap < 8) ? tap + 1 : 8;
        short8 vn0 = *(const short8*)&wspv[(tapn * 64 + mid0) * 32 + c0v];
        short8 vn1 = *(const short8*)&wspv[(tapn * 64 + mid1) * 32 + c0v];
        const int dyb = (wr + dyrow) * 66;
        short8 a[4];
#pragma unroll
        for (int mf = 0; mf < 4; ++mf) {
            int col = mf * 16 + l15 + dx;
            a[mf] = *(const short8*)&sV[(dyb + col) * 32 + (c0v ^ (((col + 3) & 3) << 3))];
        }
        __builtin_amdgcn_s_setprio(1);
#pragma unroll
        for (int mf = 0; mf < 4; ++mf) {
            acc[mf][0] = MF(a[mf], vc0, acc[mf][0]);
            acc[mf][1] = MF(a[mf], vc1, acc[mf][1]);
        }
        __builtin_amdgcn_s_setprio(0);
        vc0 = vn0; vc1 = vn1;
    }

    const float w2v0 = sp_w2[mid0], w2v1 = sp_w2[mid1];
    const float b1v0 = sp_b1[mid0], b1v1 = sp_b1[mid1];
    float4 part[4];
#pragma unroll
    for (int mf = 0; mf < 4; ++mf) {
#pragma unroll
        for (int rr = 0; rr < 4; ++rr) {
            float s = fmaf(w2v0, fmaxf(acc[mf][0][rr] + b1v0, 0.f),
                           w2v1 * fmaxf(acc[mf][1][rr] + b1v1, 0.f));
            s += __shfl_xor(s, 1, 64);
            s += __shfl_xor(s, 2, 64);
            s += __shfl_xor(s, 4, 64);
            s += __shfl_xor(s, 8, 64);
            ((float*)&part[mf])[rr] = s;
        }
    }
    __syncthreads();
    float4* sP = (float4*)sV;
    if (wc == 1 && l15 == 0) {
#pragma unroll
        for (int mf = 0; mf < 4; ++mf) sP[(wr * 4 + mf) * 4 + lg] = part[mf];
    }
    __syncthreads();
    if (wc == 0 && l15 == 0) {
        const float b2 = sp_b2[0];
#pragma unroll
        for (int mf = 0; mf < 4; ++mf) {
            float4 o = sP[(wr * 4 + mf) * 4 + lg];
            float4 vout;
            vout.x = 1.f / (1.f + __expf(-(part[mf].x + o.x + b2)));
            vout.y = 1.f / (1.f + __expf(-(part[mf].y + o.y + b2)));
            vout.z = 1.f / (1.f + __expf(-(part[mf].z + o.z + b2)));
            vout.w = 1.f / (1.f + __expf(-(part[mf].w + o.w + b2)));
            *(float4*)&out_sp[(size_t)n * HW + (y0 + wr) * 256 + x0 + mf * 16 + lg * 4] = vout;
        }
    }
}

// ---------------------------------------------------------------------------
extern "C" void kernel_launch(void* const* d_in, const int* in_sizes, int n_in,
                              void* d_out, int out_size, void* d_ws, size_t ws_size,
                              hipStream_t stream)
{
    (void)in_sizes; (void)n_in; (void)out_size; (void)ws_size;
    const float* ego_vox     = (const float*)d_in[0];
    const float* ego_feat    = (const float*)d_in[1];
    const float* ego_det     = (const float*)d_in[2];
    const float* collab_vox  = (const float*)d_in[3];
    const float* collab_feat = (const float*)d_in[4];
    const float* collab_det  = (const float*)d_in[5];
    const float* q_w   = (const float*)d_in[6];
    const float* ch_w1 = (const float*)d_in[7];
    const float* ch_w2 = (const float*)d_in[8];
    const float* k_w1  = (const float*)d_in[9];
    const float* k_w2  = (const float*)d_in[10];
    const float* k_w3  = (const float*)d_in[11];
    const float* sp_w1 = (const float*)d_in[12];
    const float* sp_b1 = (const float*)d_in[13];
    const float* sp_w2 = (const float*)d_in[14];
    const float* sp_b2 = (const float*)d_in[15];
    const float* gr_w1 = (const float*)d_in[16];
    const float* gr_b1 = (const float*)d_in[17];
    const float* gr_w2 = (const float*)d_in[18];
    const float* gr_b2 = (const float*)d_in[19];
    const float* se_w1 = (const float*)d_in[20];
    const float* se_b1 = (const float*)d_in[21];
    const float* se_w2 = (const float*)d_in[22];
    const float* se_b2 = (const float*)d_in[23];

    float* out = (float*)d_out;
    float* o_contrib = out;                 // [5,3,256,256]
    float* o_qk      = out + 983040;        // [5,3,256,256]
    float* o_sp      = out + 1966080;       // [5,1,256,256]
    float* o_gran    = out + 2293760;       // [5,3]
    float* o_sem     = out + 2293775;       // [5,32,256,256]
    float* o_chan    = out + 12779535;      // [64]

    float* wsf  = (float*)d_ws;
    float* pool = wsf;
    float* qwT  = wsf + 464;
    float* kw1T = wsf + 1488;
    float* kw2T = wsf + 1616;
    float* kw3T = wsf + 2640;
    unsigned short* wbf  = (unsigned short*)(wsf + 122576);
    unsigned short* w2bf = (unsigned short*)(wsf + 159440);
    unsigned short* wspf = (unsigned short*)(wsf + 161488);
    unsigned short* wspv = (unsigned short*)(wsf + 179920);
    unsigned short* featNHWC = (unsigned short*)(wsf + 189136);
    unsigned short* vdNHWC   = (unsigned short*)(wsf + 10674896);
    float* partials          = wsf + 15917776;

    k_prep<<<288, 256, 0, stream>>>(se_w1, se_w2, sp_w1, wbf, w2bf, wspf, wspv);
    k_transpose<<<4, 256, 0, stream>>>(q_w, k_w1, k_w2, k_w3, qwT, kw1T, kw2T, kw3T);

    k_contrib_qk<<<1280, 256, 0, stream>>>(
        ego_vox, ego_feat, ego_det, collab_vox, collab_feat, collab_det,
        qwT, kw1T, kw2T, kw3T, o_contrib, o_qk);

    k_prep_nhwc<<<dim3(256, 6), 256, 0, stream>>>(
        ego_feat, collab_vox, collab_feat, collab_det,
        featNHWC, vdNHWC, partials);
    k_pool2<<<464, 256, 0, stream>>>(partials, pool);
    k_mlps<<<1, 192, 0, stream>>>(pool, ch_w1, ch_w2, gr_w1, gr_b1, gr_w2, gr_b2,
                                  o_gran, o_chan);

    k_spatial_nhwc<<<1280, 512, 0, stream>>>(
        featNHWC, vdNHWC, wspf, wspv, sp_b1, sp_w2, sp_b2, o_sp);
    k_sem_nhwc<<<2560, 256, 0, stream>>>(
        featNHWC, wbf, w2bf, se_b1, se_b2, o_sem);
}